// Round 2
// baseline (508.289 us; speedup 1.0000x reference)
//
#include <hip/hip_runtime.h>
#include <hip/hip_bf16.h>

#define T_SEQ 2048
#define HID_DIM 2048
#define NH 32
#define NKV 8
#define HD 64

typedef __attribute__((ext_vector_type(8))) short short8;
typedef __attribute__((ext_vector_type(4))) float f32x4;

#define MFMA16(a, b, c) __builtin_amdgcn_mfma_f32_16x16x32_bf16((a), (b), (c), 0, 0, 0)

static __device__ __forceinline__ ushort f2bf(float f) {
  union { __hip_bfloat16 h; ushort u; } un;
  un.h = __float2bfloat16(f);
  return un.u;
}
static __device__ __forceinline__ float bf2f(ushort u) {
  union { ushort u; __hip_bfloat16 h; } un;
  un.u = u;
  return __bfloat162float(un.h);
}

static __device__ __forceinline__ void gload_lds16(const void* g, void* l) {
  __builtin_amdgcn_global_load_lds(
      (const __attribute__((address_space(1))) void*)g,
      (__attribute__((address_space(3))) void*)l, 16, 0, 0);
}

// ---------------- fp32 -> bf16 cast (float4 vectorized) ----------------
__global__ __launch_bounds__(256) void cast_kernel(const float* __restrict__ in,
                                                   ushort* __restrict__ out, int n4) {
  int i = blockIdx.x * 256 + threadIdx.x;
  if (i >= n4) return;
  const float4 v = reinterpret_cast<const float4*>(in)[i];
  ushort4 o;
  o.x = f2bf(v.x); o.y = f2bf(v.y); o.z = f2bf(v.z); o.w = f2bf(v.w);
  reinterpret_cast<ushort4*>(out)[i] = o;
}

// ---------------- GEMM: C[M,N] = A[M,K] * W[N,K]^T (bf16 in, OutT out) ---
__device__ __forceinline__ void store_c(float* p, float v) { *p = v; }
__device__ __forceinline__ void store_c(ushort* p, float v) { *p = f2bf(v); }

template <typename OutT>
__global__ __launch_bounds__(256) void gemm_bt(const ushort* __restrict__ A,
                                               const ushort* __restrict__ W,
                                               OutT* __restrict__ C,
                                               int M, int N, int K) {
  __shared__ __align__(16) ushort As[128][32];
  __shared__ __align__(16) ushort Bs[128][32];
  const int brow = blockIdx.y * 128, bcol = blockIdx.x * 128;
  const int tid = threadIdx.x;
  const int wid = tid >> 6, lane = tid & 63, l15 = lane & 15, lhi = lane >> 4;
  const int wr = wid >> 1, wc = wid & 1;
  const int srow = tid >> 2, scol = (tid & 3) * 8;  // staging: 16B per thread

  f32x4 acc[4][4] = {};

  const ushort* a0 = A + (size_t)(brow + srow) * K + scol;
  const ushort* a1 = A + (size_t)(brow + 64 + srow) * K + scol;
  const ushort* w0 = W + (size_t)(bcol + srow) * K + scol;
  const ushort* w1 = W + (size_t)(bcol + 64 + srow) * K + scol;
  ushort* lA0 = &As[0][0] + tid * 8;
  ushort* lA1 = &As[0][0] + 2048 + tid * 8;
  ushort* lB0 = &Bs[0][0] + tid * 8;
  ushort* lB1 = &Bs[0][0] + 2048 + tid * 8;

  for (int k0 = 0; k0 < K; k0 += 32) {
    gload_lds16(a0 + k0, lA0);
    gload_lds16(a1 + k0, lA1);
    gload_lds16(w0 + k0, lB0);
    gload_lds16(w1 + k0, lB1);
    __syncthreads();
    short8 af[4], bfr[4];
#pragma unroll
    for (int m = 0; m < 4; ++m)
      af[m] = *(const short8*)&As[wr * 64 + m * 16 + l15][lhi * 8];
#pragma unroll
    for (int n = 0; n < 4; ++n)
      bfr[n] = *(const short8*)&Bs[wc * 64 + n * 16 + l15][lhi * 8];
#pragma unroll
    for (int m = 0; m < 4; ++m)
#pragma unroll
      for (int n = 0; n < 4; ++n)
        acc[m][n] = MFMA16(af[m], bfr[n], acc[m][n]);
    __syncthreads();
  }

#pragma unroll
  for (int m = 0; m < 4; ++m) {
    const int row = brow + wr * 64 + m * 16 + lhi * 4;
#pragma unroll
    for (int n = 0; n < 4; ++n) {
      const int col = bcol + wc * 64 + n * 16 + l15;
#pragma unroll
      for (int r = 0; r < 4; ++r)
        store_c(&C[(size_t)(row + r) * N + col], acc[m][n][r]);
    }
  }
}

// ---------------- RoPE in-place on fused QKV buffer; Q pre-scaled -------
__global__ __launch_bounds__(256) void rope_kernel(ushort* __restrict__ qkv,
                                                   const float* __restrict__ ct,
                                                   const float* __restrict__ st) {
  const int bt = blockIdx.x;  // b*T + t
  ushort* row = qkv + (size_t)bt * 3072;
  const float* c = ct + (size_t)bt * 64;
  const float* s = st + (size_t)bt * 64;
  const int tid = threadIdx.x;
#pragma unroll
  for (int it = 0; it < 5; ++it) {
    const int idx = it * 256 + tid;          // 0..1023 Q pairs, 1024..1279 K pairs
    const bool isQ = idx < 1024;
    const int sub = isQ ? idx : idx - 1024;
    const int hh = sub >> 5;
    const int p = sub & 31;
    const int col = (isQ ? 0 : HID_DIM) + hh * 64 + p;
    const float x1 = bf2f(row[col]);
    const float x2 = bf2f(row[col + 32]);
    const float cc = c[p], ss = s[p];
    float y1 = x1 * cc - x2 * ss;
    float y2 = x2 * cc + x1 * ss;
    if (isQ) { y1 *= 0.125f; y2 *= 0.125f; }   // SCALE = HD^-0.5, exact in bf16
    row[col] = f2bf(y1);
    row[col + 32] = f2bf(y2);
  }
}

// ---------------- causal GQA flash attention ---------------------------
// grid: (32 q-tiles, B*NH). 256 threads = 4 waves, each owns 16 q-rows.
__global__ __launch_bounds__(256) void attn_kernel(const ushort* __restrict__ qkv,
                                                   ushort* __restrict__ out) {
  __shared__ __align__(16) ushort Kt[64][72];
  __shared__ __align__(16) ushort Vt[64][72];
  __shared__ __align__(16) ushort Pt[64][72];
  const int qt = blockIdx.x;
  const int bh = blockIdx.y;
  const int b = bh >> 5, h = bh & 31, hkv = h >> 2;
  const int tid = threadIdx.x;
  const int wid = tid >> 6, lane = tid & 63, l15 = lane & 15, lhi = lane >> 4;
  const int qbase = qt * 64;

  // Q fragments (pre-scaled, RoPE'd) held in registers for the whole block
  const size_t qrow_off = (size_t)(b * T_SEQ + qbase + wid * 16 + l15) * 3072 + h * 64;
  const short8 qf0 = *(const short8*)(qkv + qrow_off + lhi * 8);
  const short8 qf1 = *(const short8*)(qkv + qrow_off + 32 + lhi * 8);

  f32x4 oacc[4] = {};
  float mrun[4], lrun[4];
#pragma unroll
  for (int r = 0; r < 4; ++r) { mrun[r] = -1e30f; lrun[r] = 0.f; }

  const int srow = tid >> 2;           // staging row 0..63
  const int scol = (tid & 3) * 16;     // staging col 0/16/32/48

  for (int kt = 0; kt <= qt; ++kt) {
    // stage K row-major, V transposed
    const ushort* ks = qkv + (size_t)(b * T_SEQ + kt * 64 + srow) * 3072 +
                       HID_DIM + hkv * 64 + scol;
    short8 kv0 = *(const short8*)ks;
    short8 kv1 = *(const short8*)(ks + 8);
    short8 vv0 = *(const short8*)(ks + 512);
    short8 vv1 = *(const short8*)(ks + 520);
    *(short8*)&Kt[srow][scol] = kv0;
    *(short8*)&Kt[srow][scol + 8] = kv1;
#pragma unroll
    for (int i = 0; i < 8; ++i) {
      Vt[scol + i][srow] = (ushort)vv0[i];
      Vt[scol + 8 + i][srow] = (ushort)vv1[i];
    }
    __syncthreads();

    // S = Q K^T  (16 q-rows x 64 k-cols per wave)
    f32x4 sacc[4] = {};
#pragma unroll
    for (int n = 0; n < 4; ++n) {
      short8 kb0 = *(const short8*)&Kt[n * 16 + l15][lhi * 8];
      short8 kb1 = *(const short8*)&Kt[n * 16 + l15][32 + lhi * 8];
      sacc[n] = MFMA16(qf0, kb0, sacc[n]);
      sacc[n] = MFMA16(qf1, kb1, sacc[n]);
    }

    const bool diag = (kt == qt);
#pragma unroll
    for (int r = 0; r < 4; ++r) {
      const int qrl = wid * 16 + lhi * 4 + r;  // local q-row in tile
      if (diag) {
#pragma unroll
        for (int n = 0; n < 4; ++n)
          if (n * 16 + l15 > qrl) sacc[n][r] = -1e30f;
      }
      float mx = fmaxf(fmaxf(sacc[0][r], sacc[1][r]), fmaxf(sacc[2][r], sacc[3][r]));
      mx = fmaxf(mx, __shfl_xor(mx, 1));
      mx = fmaxf(mx, __shfl_xor(mx, 2));
      mx = fmaxf(mx, __shfl_xor(mx, 4));
      mx = fmaxf(mx, __shfl_xor(mx, 8));
      const float mnew = fmaxf(mrun[r], mx);
      const float alpha = __expf(mrun[r] - mnew);
      float rs = 0.f;
#pragma unroll
      for (int n = 0; n < 4; ++n) {
        const float p = __expf(sacc[n][r] - mnew);
        sacc[n][r] = p;
        rs += p;
      }
      rs += __shfl_xor(rs, 1);
      rs += __shfl_xor(rs, 2);
      rs += __shfl_xor(rs, 4);
      rs += __shfl_xor(rs, 8);
      lrun[r] = lrun[r] * alpha + rs;
      mrun[r] = mnew;
#pragma unroll
      for (int n = 0; n < 4; ++n) {
        oacc[n][r] *= alpha;
        Pt[qrl][n * 16 + l15] = f2bf(sacc[n][r]);  // wave-private rows
      }
    }

    // O += P V   (P via wave-private LDS redistribution, V^T in LDS)
    const short8 pa0 = *(const short8*)&Pt[wid * 16 + l15][lhi * 8];
    const short8 pa1 = *(const short8*)&Pt[wid * 16 + l15][32 + lhi * 8];
#pragma unroll
    for (int n = 0; n < 4; ++n) {
      short8 vb0 = *(const short8*)&Vt[n * 16 + l15][lhi * 8];
      short8 vb1 = *(const short8*)&Vt[n * 16 + l15][32 + lhi * 8];
      oacc[n] = MFMA16(pa0, vb0, oacc[n]);
      oacc[n] = MFMA16(pa1, vb1, oacc[n]);
    }
    __syncthreads();
  }

  float inv[4];
#pragma unroll
  for (int r = 0; r < 4; ++r) inv[r] = 1.f / lrun[r];
#pragma unroll
  for (int n = 0; n < 4; ++n)
#pragma unroll
    for (int r = 0; r < 4; ++r) {
      const size_t orow = (size_t)(b * T_SEQ + qbase + wid * 16 + lhi * 4 + r);
      out[orow * 2048 + h * 64 + n * 16 + l15] = f2bf(oacc[n][r] * inv[r]);
    }
}

// -----------------------------------------------------------------------
extern "C" void kernel_launch(void* const* d_in, const int* in_sizes, int n_in,
                              void* d_out, int out_size, void* d_ws, size_t ws_size,
                              hipStream_t stream) {
  const float* hs   = (const float*)d_in[0];
  const float* cosb = (const float*)d_in[1];
  const float* sinb = (const float*)d_in[2];
  const float* wq   = (const float*)d_in[3];
  const float* wk   = (const float*)d_in[4];
  const float* wv   = (const float*)d_in[5];
  const float* wo   = (const float*)d_in[6];
  float* out = (float*)d_out;

  char* ws = (char*)d_ws;
  ushort* hsb   = (ushort*)(ws);                               // 4096x2048 bf16 (16 MB)
  ushort* wqkvb = (ushort*)(ws + 16777216);                    // 3072x2048 bf16 (12.6 MB)
  ushort* wob   = (ushort*)(ws + 16777216 + 12582912);         // 2048x2048 bf16 (8.4 MB)
  ushort* qkv   = (ushort*)(ws + 16777216 + 12582912 + 8388608); // 4096x3072 bf16 (25 MB)
  ushort* attno = hsb;  // alias: hs_bf16 dead after QKV GEMM

  // casts
  cast_kernel<<<8192, 256, 0, stream>>>(hs, hsb, 2097152);
  cast_kernel<<<4096, 256, 0, stream>>>(wq, wqkvb, 1048576);
  cast_kernel<<<1024, 256, 0, stream>>>(wk, wqkvb + 4194304, 262144);
  cast_kernel<<<1024, 256, 0, stream>>>(wv, wqkvb + 5242880, 262144);
  cast_kernel<<<4096, 256, 0, stream>>>(wo, wob, 1048576);

  // fused QKV projection: [4096,3072] = hs_bf16 @ [wq;wk;wv]^T
  gemm_bt<ushort><<<dim3(24, 32), 256, 0, stream>>>(hsb, wqkvb, qkv, 4096, 3072, 2048);

  // RoPE (in-place, Q pre-scaled by 0.125)
  rope_kernel<<<4096, 256, 0, stream>>>(qkv, cosb, sinb);

  // causal GQA flash attention -> attno [4096, 2048] bf16 (b,t,h,d)
  attn_kernel<<<dim3(32, 64), 256, 0, stream>>>(qkv, attno);

  // output projection -> fp32 out
  gemm_bt<float><<<dim3(16, 32), 256, 0, stream>>>(attno, wob, out, 4096, 2048, 2048);
}

// Round 3
// 462.664 us; speedup vs baseline: 1.0986x; 1.0986x over previous
//
#include <hip/hip_runtime.h>
#include <hip/hip_bf16.h>

#define T_SEQ 2048
#define HID_DIM 2048

typedef __attribute__((ext_vector_type(8))) short short8;
typedef __attribute__((ext_vector_type(4))) float f32x4;

#define MFMA16(a, b, c) __builtin_amdgcn_mfma_f32_16x16x32_bf16((a), (b), (c), 0, 0, 0)

static __device__ __forceinline__ ushort f2bf(float f) {
  union { __hip_bfloat16 h; ushort u; } un;
  un.h = __float2bfloat16(f);
  return un.u;
}
static __device__ __forceinline__ float bf2f(ushort u) {
  union { ushort u; __hip_bfloat16 h; } un;
  un.u = u;
  return __bfloat162float(un.h);
}

static __device__ __forceinline__ void gload_lds16(const void* g, void* l) {
  __builtin_amdgcn_global_load_lds(
      (const __attribute__((address_space(1))) void*)g,
      (__attribute__((address_space(3))) void*)l, 16, 0, 0);
}

// ---------------- fp32 -> bf16 cast (float4 vectorized) ----------------
__global__ __launch_bounds__(256) void cast_kernel(const float* __restrict__ in,
                                                   ushort* __restrict__ out, int n4) {
  int i = blockIdx.x * 256 + threadIdx.x;
  if (i >= n4) return;
  const float4 v = reinterpret_cast<const float4*>(in)[i];
  ushort4 o;
  o.x = f2bf(v.x); o.y = f2bf(v.y); o.z = f2bf(v.z); o.w = f2bf(v.w);
  reinterpret_cast<ushort4*>(out)[i] = o;
}

// ---------------- GEMM: C[M,N] = A[M,K] * W[N,K]^T ----------------------
// MODE 0: plain float C (stride N).  MODE 2: QKV split — cols<2560 go to C
// (ushort, stride 2560), cols>=2560 (the V projection) go TRANSPOSED to
// vT[b][hkv][d][t] so attention can stage V^T with global_load_lds.
__device__ __forceinline__ void store_c(float* p, float v) { *p = v; }
__device__ __forceinline__ void store_c(ushort* p, float v) { *p = f2bf(v); }

template <int MODE, typename OutT>
__global__ __launch_bounds__(256) void gemm_bt(const ushort* __restrict__ A,
                                               const ushort* __restrict__ W,
                                               OutT* __restrict__ C,
                                               ushort* __restrict__ vTout,
                                               int M, int N, int K) {
  __shared__ __align__(16) ushort As[128][32];
  __shared__ __align__(16) ushort Bs[128][32];
  const int brow = blockIdx.y * 128, bcol = blockIdx.x * 128;
  const int tid = threadIdx.x;
  const int wid = tid >> 6, lane = tid & 63, l15 = lane & 15, lhi = lane >> 4;
  const int wr = wid >> 1, wc = wid & 1;
  const int srow = tid >> 2, scol = (tid & 3) * 8;

  f32x4 acc[4][4] = {};

  const ushort* a0 = A + (size_t)(brow + srow) * K + scol;
  const ushort* a1 = A + (size_t)(brow + 64 + srow) * K + scol;
  const ushort* w0 = W + (size_t)(bcol + srow) * K + scol;
  const ushort* w1 = W + (size_t)(bcol + 64 + srow) * K + scol;
  ushort* lA0 = &As[0][0] + tid * 8;
  ushort* lA1 = &As[0][0] + 2048 + tid * 8;
  ushort* lB0 = &Bs[0][0] + tid * 8;
  ushort* lB1 = &Bs[0][0] + 2048 + tid * 8;

  for (int k0 = 0; k0 < K; k0 += 32) {
    gload_lds16(a0 + k0, lA0);
    gload_lds16(a1 + k0, lA1);
    gload_lds16(w0 + k0, lB0);
    gload_lds16(w1 + k0, lB1);
    __syncthreads();
    short8 af[4], bfr[4];
#pragma unroll
    for (int m = 0; m < 4; ++m)
      af[m] = *(const short8*)&As[wr * 64 + m * 16 + l15][lhi * 8];
#pragma unroll
    for (int n = 0; n < 4; ++n)
      bfr[n] = *(const short8*)&Bs[wc * 64 + n * 16 + l15][lhi * 8];
#pragma unroll
    for (int m = 0; m < 4; ++m)
#pragma unroll
      for (int n = 0; n < 4; ++n)
        acc[m][n] = MFMA16(af[m], bfr[n], acc[m][n]);
    __syncthreads();
  }

  if (MODE == 2 && bcol >= 2560) {
    // V projection -> vT[(b*8+hkv)*64 + d][t], 4 consecutive t per thread
#pragma unroll
    for (int m = 0; m < 4; ++m) {
      const int row = brow + wr * 64 + m * 16 + lhi * 4;
      const int bb = row >> 11, t = row & 2047;
#pragma unroll
      for (int n = 0; n < 4; ++n) {
        const int cv = bcol + wc * 64 + n * 16 + l15 - 2560;
        const int hk = cv >> 6, dd = cv & 63;
        ushort4 o;
        o.x = f2bf(acc[m][n][0]); o.y = f2bf(acc[m][n][1]);
        o.z = f2bf(acc[m][n][2]); o.w = f2bf(acc[m][n][3]);
        *(ushort4*)&vTout[(size_t)((bb * 8 + hk) * 64 + dd) * 2048 + t] = o;
      }
    }
  } else {
    const int cstride = (MODE == 2) ? 2560 : N;
#pragma unroll
    for (int m = 0; m < 4; ++m) {
      const int row = brow + wr * 64 + m * 16 + lhi * 4;
#pragma unroll
      for (int n = 0; n < 4; ++n) {
        const int col = bcol + wc * 64 + n * 16 + l15;
#pragma unroll
        for (int r = 0; r < 4; ++r)
          store_c(&C[(size_t)(row + r) * cstride + col], acc[m][n][r]);
      }
    }
  }
}

// ---------------- RoPE in-place on QK buffer (stride 2560); Q pre-scaled -
__global__ __launch_bounds__(256) void rope_kernel(ushort* __restrict__ qkv,
                                                   const float* __restrict__ ct,
                                                   const float* __restrict__ st) {
  const int bt = blockIdx.x;
  ushort* row = qkv + (size_t)bt * 2560;
  const float* c = ct + (size_t)bt * 64;
  const float* s = st + (size_t)bt * 64;
  const int tid = threadIdx.x;
#pragma unroll
  for (int it = 0; it < 5; ++it) {
    const int idx = it * 256 + tid;  // 0..1023 Q pairs, 1024..1279 K pairs
    const bool isQ = idx < 1024;
    const int sub = isQ ? idx : idx - 1024;
    const int hh = sub >> 5;
    const int p = sub & 31;
    const int col = (isQ ? 0 : 2048) + hh * 64 + p;
    const float x1 = bf2f(row[col]);
    const float x2 = bf2f(row[col + 32]);
    const float cc = c[p], ss = s[p];
    float y1 = x1 * cc - x2 * ss;
    float y2 = x2 * cc + x1 * ss;
    if (isQ) { y1 *= 0.125f; y2 *= 0.125f; }
    row[col] = f2bf(y1);
    row[col + 32] = f2bf(y2);
  }
}

// ---------------- causal GQA flash attention ---------------------------
// grid (16, 64): block bx handles q-tiles qa=bx and qb=31-bx (balanced: 33
// q-tile-steps each). K and V^T staged via global_load_lds with XOR-swizzle
// applied on the per-lane GLOBAL source (LDS written linearly), reads use
// the matching swizzled ds_read_b128.
__global__ __launch_bounds__(256, 4) void attn_kernel(const ushort* __restrict__ qkv,
                                                      const ushort* __restrict__ vT,
                                                      ushort* __restrict__ out) {
  __shared__ __align__(16) ushort Kt[4096];   // [kv][d] 64x64, XOR-swizzled
  __shared__ __align__(16) ushort Vt[4096];   // [d][kv] 64x64, XOR-swizzled
  __shared__ __align__(16) ushort Pt[64][72];
  const int bx = blockIdx.x, bh = blockIdx.y;
  const int b = bh >> 5, h = bh & 31, hkv = h >> 2;
  const int tid = threadIdx.x;
  const int wid = tid >> 6, lane = tid & 63, l15 = lane & 15, lhi = lane >> 4;
  const int qa = bx, qb = 31 - bx;

  short8 qA0, qA1, qB0, qB1;
  {
    const size_t offA = (size_t)(b * T_SEQ + qa * 64 + wid * 16 + l15) * 2560 + h * 64;
    qA0 = *(const short8*)(qkv + offA + lhi * 8);
    qA1 = *(const short8*)(qkv + offA + 32 + lhi * 8);
    const size_t offB = (size_t)(b * T_SEQ + qb * 64 + wid * 16 + l15) * 2560 + h * 64;
    qB0 = *(const short8*)(qkv + offB + lhi * 8);
    qB1 = *(const short8*)(qkv + offB + 32 + lhi * 8);
  }

  f32x4 oA[4] = {}, oB[4] = {};
  float mA[4], lA[4], mB[4], lB[4];
#pragma unroll
  for (int r = 0; r < 4; ++r) { mA[r] = mB[r] = -1e30f; lA[r] = lB[r] = 0.f; }

  const int srow = tid >> 3, sgrp = tid & 7;
  const int d0s = ((sgrp ^ (srow & 7)) * 8);  // swizzled source column (elems)
  const ushort* kb_g = qkv + (size_t)b * T_SEQ * 2560 + 2048 + hkv * 64;
  const ushort* vb_g = vT + (size_t)(b * 8 + hkv) * 64 * 2048;
  ushort* ldsK = Kt + tid * 8;
  ushort* ldsV = Vt + tid * 8;

  auto process = [&](short8 q0, short8 q1, f32x4* o, float* mr, float* lr, bool diag) {
    f32x4 s[4] = {};
#pragma unroll
    for (int n = 0; n < 4; ++n) {
      const int kv = n * 16 + l15;
      const int sw = (kv & 7) << 4;
      const short8 k0 = *(const short8*)((const char*)Kt + kv * 128 + ((lhi * 16) ^ sw));
      const short8 k1 = *(const short8*)((const char*)Kt + kv * 128 + ((64 + lhi * 16) ^ sw));
      s[n] = MFMA16(q0, k0, s[n]);
      s[n] = MFMA16(q1, k1, s[n]);
    }
#pragma unroll
    for (int r = 0; r < 4; ++r) {
      const int qrl = wid * 16 + lhi * 4 + r;
      if (diag) {
#pragma unroll
        for (int n = 0; n < 4; ++n)
          if (n * 16 + l15 > qrl) s[n][r] = -1e30f;
      }
      float mx = fmaxf(fmaxf(s[0][r], s[1][r]), fmaxf(s[2][r], s[3][r]));
      mx = fmaxf(mx, __shfl_xor(mx, 1));
      mx = fmaxf(mx, __shfl_xor(mx, 2));
      mx = fmaxf(mx, __shfl_xor(mx, 4));
      mx = fmaxf(mx, __shfl_xor(mx, 8));
      const float mn = fmaxf(mr[r], mx);
      const float al = __expf(mr[r] - mn);
      float rs = 0.f;
#pragma unroll
      for (int n = 0; n < 4; ++n) {
        const float p = __expf(s[n][r] - mn);
        s[n][r] = p;
        rs += p;
      }
      rs += __shfl_xor(rs, 1); rs += __shfl_xor(rs, 2);
      rs += __shfl_xor(rs, 4); rs += __shfl_xor(rs, 8);
      lr[r] = lr[r] * al + rs;
      mr[r] = mn;
#pragma unroll
      for (int n = 0; n < 4; ++n) {
        o[n][r] *= al;
        Pt[qrl][n * 16 + l15] = f2bf(s[n][r]);
      }
    }
    const short8 p0 = *(const short8*)&Pt[wid * 16 + l15][lhi * 8];
    const short8 p1 = *(const short8*)&Pt[wid * 16 + l15][32 + lhi * 8];
#pragma unroll
    for (int n = 0; n < 4; ++n) {
      const int dv = n * 16 + l15;
      const int sw = (dv & 7) << 4;
      const short8 v0 = *(const short8*)((const char*)Vt + dv * 128 + ((lhi * 16) ^ sw));
      const short8 v1 = *(const short8*)((const char*)Vt + dv * 128 + ((64 + lhi * 16) ^ sw));
      o[n] = MFMA16(p0, v0, o[n]);
      o[n] = MFMA16(p1, v1, o[n]);
    }
  };

  for (int kt = 0; kt <= qb; ++kt) {
    const int ktb = kt * 64;
    gload_lds16(kb_g + (size_t)(ktb + srow) * 2560 + d0s, ldsK);
    gload_lds16(kb_g + (size_t)(ktb + 32 + srow) * 2560 + d0s, ldsK + 2048);
    gload_lds16(vb_g + (size_t)srow * 2048 + ktb + d0s, ldsV);
    gload_lds16(vb_g + (size_t)(32 + srow) * 2048 + ktb + d0s, ldsV + 2048);
    __syncthreads();
    process(qB0, qB1, oB, mB, lB, kt == qb);
    if (kt <= qa) process(qA0, qA1, oA, mA, lA, kt == qa);
    __syncthreads();
  }

  auto wout = [&](int qt, f32x4* o, float* lr) {
#pragma unroll
    for (int r = 0; r < 4; ++r) {
      const float inv = 1.f / lr[r];
      const size_t orow = (size_t)(b * T_SEQ + qt * 64 + wid * 16 + lhi * 4 + r);
#pragma unroll
      for (int n = 0; n < 4; ++n)
        out[orow * 2048 + h * 64 + n * 16 + l15] = f2bf(o[n][r] * inv);
    }
  };
  wout(qa, oA, lA);
  wout(qb, oB, lB);
}

// -----------------------------------------------------------------------
extern "C" void kernel_launch(void* const* d_in, const int* in_sizes, int n_in,
                              void* d_out, int out_size, void* d_ws, size_t ws_size,
                              hipStream_t stream) {
  const float* hs   = (const float*)d_in[0];
  const float* cosb = (const float*)d_in[1];
  const float* sinb = (const float*)d_in[2];
  const float* wq   = (const float*)d_in[3];
  const float* wk   = (const float*)d_in[4];
  const float* wv   = (const float*)d_in[5];
  const float* wo   = (const float*)d_in[6];
  float* out = (float*)d_out;

  char* ws = (char*)d_ws;
  ushort* hsb   = (ushort*)(ws);                    // 4096x2048 bf16 (16 MB)
  ushort* wqkvb = (ushort*)(ws + 16777216);         // 3072x2048 bf16 (12.6 MB)
  ushort* wob   = (ushort*)(ws + 29360128);         // 2048x2048 bf16 (8.4 MB)
  ushort* qkvQK = (ushort*)(ws + 37748736);         // 4096x2560 bf16 (21 MB)
  ushort* vTb   = (ushort*)(ws + 58720256);         // 16x64x2048 bf16 (4 MB)
  ushort* attno = hsb;  // alias: hs_bf16 dead after QKV GEMM

  cast_kernel<<<8192, 256, 0, stream>>>(hs, hsb, 2097152);
  cast_kernel<<<4096, 256, 0, stream>>>(wq, wqkvb, 1048576);
  cast_kernel<<<1024, 256, 0, stream>>>(wk, wqkvb + 4194304, 262144);
  cast_kernel<<<1024, 256, 0, stream>>>(wv, wqkvb + 5242880, 262144);
  cast_kernel<<<4096, 256, 0, stream>>>(wo, wob, 1048576);

  // fused QKV projection; V columns routed transposed to vTb
  gemm_bt<2, ushort><<<dim3(24, 32), 256, 0, stream>>>(hsb, wqkvb, qkvQK, vTb,
                                                       4096, 3072, 2048);

  rope_kernel<<<4096, 256, 0, stream>>>(qkvQK, cosb, sinb);

  attn_kernel<<<dim3(16, 64), 256, 0, stream>>>(qkvQK, vTb, attno);

  gemm_bt<0, float><<<dim3(16, 32), 256, 0, stream>>>(attno, wob, out, nullptr,
                                                      4096, 2048, 2048);
}

// Round 4
// 392.592 us; speedup vs baseline: 1.2947x; 1.1785x over previous
//
#include <hip/hip_runtime.h>
#include <hip/hip_bf16.h>

#define T_SEQ 2048
#define HID_DIM 2048

typedef __attribute__((ext_vector_type(8))) short short8;
typedef __attribute__((ext_vector_type(4))) float f32x4;

#define MFMA16(a, b, c) __builtin_amdgcn_mfma_f32_16x16x32_bf16((a), (b), (c), 0, 0, 0)

static __device__ __forceinline__ ushort f2bf(float f) {
  union { __hip_bfloat16 h; ushort u; } un;
  un.h = __float2bfloat16(f);
  return un.u;
}
static __device__ __forceinline__ float bf2f(ushort u) {
  union { ushort u; __hip_bfloat16 h; } un;
  un.u = u;
  return __bfloat162float(un.h);
}

static __device__ __forceinline__ void gload_lds16(const void* g, void* l) {
  __builtin_amdgcn_global_load_lds(
      (const __attribute__((address_space(1))) void*)g,
      (__attribute__((address_space(3))) void*)l, 16, 0, 0);
}

// ---------------- fp32 -> bf16 cast (float4 vectorized) ----------------
__global__ __launch_bounds__(256) void cast_kernel(const float* __restrict__ in,
                                                   ushort* __restrict__ out, int n4) {
  int i = blockIdx.x * 256 + threadIdx.x;
  if (i >= n4) return;
  const float4 v = reinterpret_cast<const float4*>(in)[i];
  ushort4 o;
  o.x = f2bf(v.x); o.y = f2bf(v.y); o.z = f2bf(v.z); o.w = f2bf(v.w);
  reinterpret_cast<ushort4*>(out)[i] = o;
}

// ---------------- GEMM: C[M,N] = A[M,K] * W[N,K]^T ----------------------
__device__ __forceinline__ void store_c(float* p, float v) { *p = v; }
__device__ __forceinline__ void store_c(ushort* p, float v) { *p = f2bf(v); }

template <int MODE, typename OutT>
__global__ __launch_bounds__(256) void gemm_bt(const ushort* __restrict__ A,
                                               const ushort* __restrict__ W,
                                               OutT* __restrict__ C,
                                               ushort* __restrict__ vTout,
                                               int M, int N, int K) {
  __shared__ __align__(16) ushort As[128][32];
  __shared__ __align__(16) ushort Bs[128][32];
  const int brow = blockIdx.y * 128, bcol = blockIdx.x * 128;
  const int tid = threadIdx.x;
  const int wid = tid >> 6, lane = tid & 63, l15 = lane & 15, lhi = lane >> 4;
  const int wr = wid >> 1, wc = wid & 1;
  const int srow = tid >> 2, scol = (tid & 3) * 8;

  f32x4 acc[4][4] = {};

  const ushort* a0 = A + (size_t)(brow + srow) * K + scol;
  const ushort* a1 = A + (size_t)(brow + 64 + srow) * K + scol;
  const ushort* w0 = W + (size_t)(bcol + srow) * K + scol;
  const ushort* w1 = W + (size_t)(bcol + 64 + srow) * K + scol;
  ushort* lA0 = &As[0][0] + tid * 8;
  ushort* lA1 = &As[0][0] + 2048 + tid * 8;
  ushort* lB0 = &Bs[0][0] + tid * 8;
  ushort* lB1 = &Bs[0][0] + 2048 + tid * 8;

  for (int k0 = 0; k0 < K; k0 += 32) {
    gload_lds16(a0 + k0, lA0);
    gload_lds16(a1 + k0, lA1);
    gload_lds16(w0 + k0, lB0);
    gload_lds16(w1 + k0, lB1);
    __syncthreads();
    short8 af[4], bfr[4];
#pragma unroll
    for (int m = 0; m < 4; ++m)
      af[m] = *(const short8*)&As[wr * 64 + m * 16 + l15][lhi * 8];
#pragma unroll
    for (int n = 0; n < 4; ++n)
      bfr[n] = *(const short8*)&Bs[wc * 64 + n * 16 + l15][lhi * 8];
#pragma unroll
    for (int m = 0; m < 4; ++m)
#pragma unroll
      for (int n = 0; n < 4; ++n)
        acc[m][n] = MFMA16(af[m], bfr[n], acc[m][n]);
    __syncthreads();
  }

  if (MODE == 2 && bcol >= 2560) {
    // V projection -> vT[(b*8+hkv)*64 + d][t]
#pragma unroll
    for (int m = 0; m < 4; ++m) {
      const int row = brow + wr * 64 + m * 16 + lhi * 4;
      const int bb = row >> 11, t = row & 2047;
#pragma unroll
      for (int n = 0; n < 4; ++n) {
        const int cv = bcol + wc * 64 + n * 16 + l15 - 2560;
        const int hk = cv >> 6, dd = cv & 63;
        ushort4 o;
        o.x = f2bf(acc[m][n][0]); o.y = f2bf(acc[m][n][1]);
        o.z = f2bf(acc[m][n][2]); o.w = f2bf(acc[m][n][3]);
        *(ushort4*)&vTout[(size_t)((bb * 8 + hk) * 64 + dd) * 2048 + t] = o;
      }
    }
  } else {
    const int cstride = (MODE == 2) ? 2560 : N;
#pragma unroll
    for (int m = 0; m < 4; ++m) {
      const int row = brow + wr * 64 + m * 16 + lhi * 4;
#pragma unroll
      for (int n = 0; n < 4; ++n) {
        const int col = bcol + wc * 64 + n * 16 + l15;
#pragma unroll
        for (int r = 0; r < 4; ++r)
          store_c(&C[(size_t)(row + r) * cstride + col], acc[m][n][r]);
      }
    }
  }
}

// ---------------- RoPE in-place on QK buffer (stride 2560); Q pre-scaled -
__global__ __launch_bounds__(256) void rope_kernel(ushort* __restrict__ qkv,
                                                   const float* __restrict__ ct,
                                                   const float* __restrict__ st) {
  const int bt = blockIdx.x;
  ushort* row = qkv + (size_t)bt * 2560;
  const float* c = ct + (size_t)bt * 64;
  const float* s = st + (size_t)bt * 64;
  const int tid = threadIdx.x;
#pragma unroll
  for (int it = 0; it < 5; ++it) {
    const int idx = it * 256 + tid;
    const bool isQ = idx < 1024;
    const int sub = isQ ? idx : idx - 1024;
    const int hh = sub >> 5;
    const int p = sub & 31;
    const int col = (isQ ? 0 : 2048) + hh * 64 + p;
    const float x1 = bf2f(row[col]);
    const float x2 = bf2f(row[col + 32]);
    const float cc = c[p], ss = s[p];
    float y1 = x1 * cc - x2 * ss;
    float y2 = x2 * cc + x1 * ss;
    if (isQ) { y1 *= 0.125f; y2 *= 0.125f; }
    row[col] = f2bf(y1);
    row[col + 32] = f2bf(y2);
  }
}

// ---------------- causal GQA flash attention ---------------------------
// PROCESS is a macro over NAMED variables (no pointer/array params) so all
// per-tile state stays in registers (round-3 lambda version spilled to
// scratch: 354 MB of HBM writes). Suffix SUF is A or B.
#define PROCESS(SUF, diag_) do {                                              \
    f32x4 s_[4] = {};                                                         \
    _Pragma("unroll")                                                         \
    for (int n = 0; n < 4; ++n) {                                             \
      const int kv = n * 16 + l15;                                            \
      const int sw = (kv & 7) << 4;                                           \
      const short8 k0_ = *(const short8*)((const char*)Kt + kv * 128 + ((lhi * 16) ^ sw));      \
      const short8 k1_ = *(const short8*)((const char*)Kt + kv * 128 + ((64 + lhi * 16) ^ sw)); \
      s_[n] = MFMA16(q##SUF##0, k0_, s_[n]);                                  \
      s_[n] = MFMA16(q##SUF##1, k1_, s_[n]);                                  \
    }                                                                         \
    _Pragma("unroll")                                                         \
    for (int r = 0; r < 4; ++r) {                                             \
      const int qrl = wid * 16 + lhi * 4 + r;                                 \
      if (diag_) {                                                            \
        _Pragma("unroll")                                                     \
        for (int n = 0; n < 4; ++n)                                           \
          if (n * 16 + l15 > qrl) s_[n][r] = -1e30f;                          \
      }                                                                       \
      float mx = fmaxf(fmaxf(s_[0][r], s_[1][r]), fmaxf(s_[2][r], s_[3][r])); \
      mx = fmaxf(mx, __shfl_xor(mx, 1));                                      \
      mx = fmaxf(mx, __shfl_xor(mx, 2));                                      \
      mx = fmaxf(mx, __shfl_xor(mx, 4));                                      \
      mx = fmaxf(mx, __shfl_xor(mx, 8));                                      \
      const float mn = fmaxf(m##SUF[r], mx);                                  \
      const float al = __expf(m##SUF[r] - mn);                                \
      float rs = 0.f;                                                         \
      _Pragma("unroll")                                                       \
      for (int n = 0; n < 4; ++n) {                                           \
        const float p_ = __expf(s_[n][r] - mn);                               \
        s_[n][r] = p_;                                                        \
        rs += p_;                                                             \
      }                                                                       \
      rs += __shfl_xor(rs, 1); rs += __shfl_xor(rs, 2);                       \
      rs += __shfl_xor(rs, 4); rs += __shfl_xor(rs, 8);                       \
      l##SUF[r] = l##SUF[r] * al + rs;                                        \
      m##SUF[r] = mn;                                                         \
      _Pragma("unroll")                                                       \
      for (int n = 0; n < 4; ++n) {                                           \
        o##SUF[n][r] *= al;                                                   \
        Pt[qrl][n * 16 + l15] = f2bf(s_[n][r]);                               \
      }                                                                       \
    }                                                                         \
    {                                                                         \
      const short8 p0_ = *(const short8*)&Pt[wid * 16 + l15][lhi * 8];        \
      const short8 p1_ = *(const short8*)&Pt[wid * 16 + l15][32 + lhi * 8];   \
      _Pragma("unroll")                                                       \
      for (int n = 0; n < 4; ++n) {                                           \
        const int dv = n * 16 + l15;                                          \
        const int sw = (dv & 7) << 4;                                         \
        const short8 v0_ = *(const short8*)((const char*)Vt + dv * 128 + ((lhi * 16) ^ sw));      \
        const short8 v1_ = *(const short8*)((const char*)Vt + dv * 128 + ((64 + lhi * 16) ^ sw)); \
        o##SUF[n] = MFMA16(p0_, v0_, o##SUF[n]);                              \
        o##SUF[n] = MFMA16(p1_, v1_, o##SUF[n]);                              \
      }                                                                       \
    }                                                                         \
  } while (0)

// 1D grid of 1024 blocks. XCD-aware mapping: each XCD owns 8 consecutive bh
// (= 2 (b,hkv) K/V slices = 1 MB) so K/V re-reads stay L2-resident.
// Block handles q-tiles qa=bx and qb=31-bx (33 balanced tile-steps each).
__global__ __launch_bounds__(256, 4) void attn_kernel(const ushort* __restrict__ qkv,
                                                      const ushort* __restrict__ vT,
                                                      ushort* __restrict__ out) {
  __shared__ __align__(16) ushort Kt[4096];   // [kv][d] 64x64, XOR-swizzled
  __shared__ __align__(16) ushort Vt[4096];   // [d][kv] 64x64, XOR-swizzled
  __shared__ __align__(16) ushort Pt[64][72];
  const int bid = blockIdx.x;
  const int j = bid >> 3;
  const int bh = (bid & 7) * 8 + (j & 7);     // bijective over 0..63
  const int bx = j >> 3;                      // 0..15
  const int b = bh >> 5, h = bh & 31, hkv = h >> 2;
  const int tid = threadIdx.x;
  const int wid = tid >> 6, lane = tid & 63, l15 = lane & 15, lhi = lane >> 4;
  const int qa = bx, qb = 31 - bx;

  short8 qA0, qA1, qB0, qB1;
  {
    const size_t offA = (size_t)(b * T_SEQ + qa * 64 + wid * 16 + l15) * 2560 + h * 64;
    qA0 = *(const short8*)(qkv + offA + lhi * 8);
    qA1 = *(const short8*)(qkv + offA + 32 + lhi * 8);
    const size_t offB = (size_t)(b * T_SEQ + qb * 64 + wid * 16 + l15) * 2560 + h * 64;
    qB0 = *(const short8*)(qkv + offB + lhi * 8);
    qB1 = *(const short8*)(qkv + offB + 32 + lhi * 8);
  }

  f32x4 oA[4] = {}, oB[4] = {};
  float mA[4], lA[4], mB[4], lB[4];
#pragma unroll
  for (int r = 0; r < 4; ++r) { mA[r] = mB[r] = -1e30f; lA[r] = lB[r] = 0.f; }

  const int srow = tid >> 3, sgrp = tid & 7;
  const int d0s = ((sgrp ^ (srow & 7)) * 8);  // swizzled source column (elems)
  const ushort* kb_g = qkv + (size_t)b * T_SEQ * 2560 + 2048 + hkv * 64;
  const ushort* vb_g = vT + (size_t)(b * 8 + hkv) * 64 * 2048;
  ushort* ldsK = Kt + tid * 8;
  ushort* ldsV = Vt + tid * 8;

  for (int kt = 0; kt <= qb; ++kt) {
    const int ktb = kt * 64;
    gload_lds16(kb_g + (size_t)(ktb + srow) * 2560 + d0s, ldsK);
    gload_lds16(kb_g + (size_t)(ktb + 32 + srow) * 2560 + d0s, ldsK + 2048);
    gload_lds16(vb_g + (size_t)srow * 2048 + ktb + d0s, ldsV);
    gload_lds16(vb_g + (size_t)(32 + srow) * 2048 + ktb + d0s, ldsV + 2048);
    __syncthreads();
    PROCESS(B, kt == qb);
    if (kt <= qa) PROCESS(A, kt == qa);
    __syncthreads();
  }

#pragma unroll
  for (int r = 0; r < 4; ++r) {
    const float invA = 1.f / lA[r];
    const size_t orowA = (size_t)(b * T_SEQ + qa * 64 + wid * 16 + lhi * 4 + r);
#pragma unroll
    for (int n = 0; n < 4; ++n)
      out[orowA * 2048 + h * 64 + n * 16 + l15] = f2bf(oA[n][r] * invA);
  }
#pragma unroll
  for (int r = 0; r < 4; ++r) {
    const float invB = 1.f / lB[r];
    const size_t orowB = (size_t)(b * T_SEQ + qb * 64 + wid * 16 + lhi * 4 + r);
#pragma unroll
    for (int n = 0; n < 4; ++n)
      out[orowB * 2048 + h * 64 + n * 16 + l15] = f2bf(oB[n][r] * invB);
  }
}

// -----------------------------------------------------------------------
extern "C" void kernel_launch(void* const* d_in, const int* in_sizes, int n_in,
                              void* d_out, int out_size, void* d_ws, size_t ws_size,
                              hipStream_t stream) {
  const float* hs   = (const float*)d_in[0];
  const float* cosb = (const float*)d_in[1];
  const float* sinb = (const float*)d_in[2];
  const float* wq   = (const float*)d_in[3];
  const float* wk   = (const float*)d_in[4];
  const float* wv   = (const float*)d_in[5];
  const float* wo   = (const float*)d_in[6];
  float* out = (float*)d_out;

  char* ws = (char*)d_ws;
  ushort* hsb   = (ushort*)(ws);                    // 4096x2048 bf16 (16 MB)
  ushort* wqkvb = (ushort*)(ws + 16777216);         // 3072x2048 bf16 (12.6 MB)
  ushort* wob   = (ushort*)(ws + 29360128);         // 2048x2048 bf16 (8.4 MB)
  ushort* qkvQK = (ushort*)(ws + 37748736);         // 4096x2560 bf16 (21 MB)
  ushort* vTb   = (ushort*)(ws + 58720256);         // 16x64x2048 bf16 (4 MB)
  ushort* attno = hsb;  // alias: hs_bf16 dead after QKV GEMM

  cast_kernel<<<8192, 256, 0, stream>>>(hs, hsb, 2097152);
  cast_kernel<<<4096, 256, 0, stream>>>(wq, wqkvb, 1048576);
  cast_kernel<<<1024, 256, 0, stream>>>(wk, wqkvb + 4194304, 262144);
  cast_kernel<<<1024, 256, 0, stream>>>(wv, wqkvb + 5242880, 262144);
  cast_kernel<<<4096, 256, 0, stream>>>(wo, wob, 1048576);

  // fused QKV projection; V columns routed transposed to vTb
  gemm_bt<2, ushort><<<dim3(24, 32), 256, 0, stream>>>(hsb, wqkvb, qkvQK, vTb,
                                                       4096, 3072, 2048);

  rope_kernel<<<4096, 256, 0, stream>>>(qkvQK, cosb, sinb);

  attn_kernel<<<1024, 256, 0, stream>>>(qkvQK, vTb, attno);

  gemm_bt<0, float><<<dim3(16, 32), 256, 0, stream>>>(attno, wob, out, nullptr,
                                                      4096, 2048, 2048);
}

// Round 6
// 384.708 us; speedup vs baseline: 1.3212x; 1.0205x over previous
//
#include <hip/hip_runtime.h>
#include <hip/hip_bf16.h>

#define T_SEQ 2048
#define HID_DIM 2048

typedef __attribute__((ext_vector_type(8))) short short8;
typedef __attribute__((ext_vector_type(4))) float f32x4;

#define MFMA16(a, b, c) __builtin_amdgcn_mfma_f32_16x16x32_bf16((a), (b), (c), 0, 0, 0)

static __device__ __forceinline__ ushort f2bf(float f) {
  union { __hip_bfloat16 h; ushort u; } un;
  un.h = __float2bfloat16(f);
  return un.u;
}
static __device__ __forceinline__ float bf2f(ushort u) {
  union { ushort u; __hip_bfloat16 h; } un;
  un.u = u;
  return __bfloat162float(un.h);
}

static __device__ __forceinline__ void gload_lds16(const void* g, void* l) {
  __builtin_amdgcn_global_load_lds(
      (const __attribute__((address_space(1))) void*)g,
      (__attribute__((address_space(3))) void*)l, 16, 0, 0);
}

// ---------------- fp32 -> bf16 cast (float4 vectorized) ----------------
__global__ __launch_bounds__(256) void cast_kernel(const float* __restrict__ in,
                                                   ushort* __restrict__ out, int n4) {
  int i = blockIdx.x * 256 + threadIdx.x;
  if (i >= n4) return;
  const float4 v = reinterpret_cast<const float4*>(in)[i];
  ushort4 o;
  o.x = f2bf(v.x); o.y = f2bf(v.y); o.z = f2bf(v.z); o.w = f2bf(v.w);
  reinterpret_cast<ushort4*>(out)[i] = o;
}

// ---------------- GEMM: C[M,N] = A[M,K] * W[N,K]^T ----------------------
__device__ __forceinline__ void store_c(float* p, float v) { *p = v; }
__device__ __forceinline__ void store_c(ushort* p, float v) { *p = f2bf(v); }

template <int MODE, typename OutT>
__global__ __launch_bounds__(256) void gemm_bt(const ushort* __restrict__ A,
                                               const ushort* __restrict__ W,
                                               OutT* __restrict__ C,
                                               ushort* __restrict__ vTout,
                                               int M, int N, int K) {
  __shared__ __align__(16) ushort As[128][32];
  __shared__ __align__(16) ushort Bs[128][32];
  const int brow = blockIdx.y * 128, bcol = blockIdx.x * 128;
  const int tid = threadIdx.x;
  const int wid = tid >> 6, lane = tid & 63, l15 = lane & 15, lhi = lane >> 4;
  const int wr = wid >> 1, wc = wid & 1;
  const int srow = tid >> 2, scol = (tid & 3) * 8;

  f32x4 acc[4][4] = {};

  const ushort* a0 = A + (size_t)(brow + srow) * K + scol;
  const ushort* a1 = A + (size_t)(brow + 64 + srow) * K + scol;
  const ushort* w0 = W + (size_t)(bcol + srow) * K + scol;
  const ushort* w1 = W + (size_t)(bcol + 64 + srow) * K + scol;
  ushort* lA0 = &As[0][0] + tid * 8;
  ushort* lA1 = &As[0][0] + 2048 + tid * 8;
  ushort* lB0 = &Bs[0][0] + tid * 8;
  ushort* lB1 = &Bs[0][0] + 2048 + tid * 8;

  for (int k0 = 0; k0 < K; k0 += 32) {
    gload_lds16(a0 + k0, lA0);
    gload_lds16(a1 + k0, lA1);
    gload_lds16(w0 + k0, lB0);
    gload_lds16(w1 + k0, lB1);
    __syncthreads();
    short8 af[4], bfr[4];
#pragma unroll
    for (int m = 0; m < 4; ++m)
      af[m] = *(const short8*)&As[wr * 64 + m * 16 + l15][lhi * 8];
#pragma unroll
    for (int n = 0; n < 4; ++n)
      bfr[n] = *(const short8*)&Bs[wc * 64 + n * 16 + l15][lhi * 8];
#pragma unroll
    for (int m = 0; m < 4; ++m)
#pragma unroll
      for (int n = 0; n < 4; ++n)
        acc[m][n] = MFMA16(af[m], bfr[n], acc[m][n]);
    __syncthreads();
  }

  if (MODE == 2 && bcol >= 2560) {
    // V projection -> vT[(b*8+hkv)*64 + d][t]
#pragma unroll
    for (int m = 0; m < 4; ++m) {
      const int row = brow + wr * 64 + m * 16 + lhi * 4;
      const int bb = row >> 11, t = row & 2047;
#pragma unroll
      for (int n = 0; n < 4; ++n) {
        const int cv = bcol + wc * 64 + n * 16 + l15 - 2560;
        const int hk = cv >> 6, dd = cv & 63;
        ushort4 o;
        o.x = f2bf(acc[m][n][0]); o.y = f2bf(acc[m][n][1]);
        o.z = f2bf(acc[m][n][2]); o.w = f2bf(acc[m][n][3]);
        *(ushort4*)&vTout[(size_t)((bb * 8 + hk) * 64 + dd) * 2048 + t] = o;
      }
    }
  } else {
    const int cstride = (MODE == 2) ? 2560 : N;
#pragma unroll
    for (int m = 0; m < 4; ++m) {
      const int row = brow + wr * 64 + m * 16 + lhi * 4;
#pragma unroll
      for (int n = 0; n < 4; ++n) {
        const int col = bcol + wc * 64 + n * 16 + l15;
#pragma unroll
        for (int r = 0; r < 4; ++r)
          store_c(&C[(size_t)(row + r) * cstride + col], acc[m][n][r]);
      }
    }
  }
}

// ---------------- RoPE in-place on QK buffer (stride 2560); Q pre-scaled -
__global__ __launch_bounds__(256) void rope_kernel(ushort* __restrict__ qkv,
                                                   const float* __restrict__ ct,
                                                   const float* __restrict__ st) {
  const int bt = blockIdx.x;
  ushort* row = qkv + (size_t)bt * 2560;
  const float* c = ct + (size_t)bt * 64;
  const float* s = st + (size_t)bt * 64;
  const int tid = threadIdx.x;
#pragma unroll
  for (int it = 0; it < 5; ++it) {
    const int idx = it * 256 + tid;
    const bool isQ = idx < 1024;
    const int sub = isQ ? idx : idx - 1024;
    const int hh = sub >> 5;
    const int p = sub & 31;
    const int col = (isQ ? 0 : 2048) + hh * 64 + p;
    const float x1 = bf2f(row[col]);
    const float x2 = bf2f(row[col + 32]);
    const float cc = c[p], ss = s[p];
    float y1 = x1 * cc - x2 * ss;
    float y2 = x2 * cc + x1 * ss;
    if (isQ) { y1 *= 0.125f; y2 *= 0.125f; }
    row[col] = f2bf(y1);
    row[col + 32] = f2bf(y2);
  }
}

// ---------------- causal GQA flash attention ---------------------------
// PROCESS operates on NAMED per-tile state (round-3 pointer-param lambda
// spilled). Q fragments are RELOADED from global each tile-step (L1/L2-hot)
// instead of held persistently: with the unified VGPR/AGPR file, persistent
// Q frags + dual accumulators exceeded the 128-reg budget that
// __launch_bounds__(256,4) imposed in round 4 -> ~190 MB scratch writebacks.
// SUF is A or B; q##SUF is the tile index.
#define PROCESS(SUF, diag_) do {                                              \
    const size_t qoff_ =                                                      \
        (size_t)(b * T_SEQ + q##SUF * 64 + wid * 16 + l15) * 2560 + h * 64 +  \
        lhi * 8;                                                              \
    const short8 q0_ = *(const short8*)(qkv + qoff_);                         \
    const short8 q1_ = *(const short8*)(qkv + qoff_ + 32);                    \
    f32x4 s_[4] = {};                                                         \
    _Pragma("unroll")                                                         \
    for (int n = 0; n < 4; ++n) {                                             \
      const int kv = n * 16 + l15;                                            \
      const int sw = (kv & 7) << 4;                                           \
      const short8 k0_ = *(const short8*)((const char*)Kt + kv * 128 + ((lhi * 16) ^ sw));      \
      const short8 k1_ = *(const short8*)((const char*)Kt + kv * 128 + ((64 + lhi * 16) ^ sw)); \
      s_[n] = MFMA16(q0_, k0_, s_[n]);                                        \
      s_[n] = MFMA16(q1_, k1_, s_[n]);                                        \
    }                                                                         \
    _Pragma("unroll")                                                         \
    for (int r = 0; r < 4; ++r) {                                             \
      const int qrl = wid * 16 + lhi * 4 + r;                                 \
      if (diag_) {                                                            \
        _Pragma("unroll")                                                     \
        for (int n = 0; n < 4; ++n)                                           \
          if (n * 16 + l15 > qrl) s_[n][r] = -1e30f;                          \
      }                                                                       \
      float mx = fmaxf(fmaxf(s_[0][r], s_[1][r]), fmaxf(s_[2][r], s_[3][r])); \
      mx = fmaxf(mx, __shfl_xor(mx, 1));                                      \
      mx = fmaxf(mx, __shfl_xor(mx, 2));                                      \
      mx = fmaxf(mx, __shfl_xor(mx, 4));                                      \
      mx = fmaxf(mx, __shfl_xor(mx, 8));                                      \
      const float mn = fmaxf(m##SUF[r], mx);                                  \
      const float al = __expf(m##SUF[r] - mn);                                \
      float rs = 0.f;                                                         \
      _Pragma("unroll")                                                       \
      for (int n = 0; n < 4; ++n) {                                           \
        const float p_ = __expf(s_[n][r] - mn);                               \
        s_[n][r] = p_;                                                        \
        rs += p_;                                                             \
      }                                                                       \
      rs += __shfl_xor(rs, 1); rs += __shfl_xor(rs, 2);                       \
      rs += __shfl_xor(rs, 4); rs += __shfl_xor(rs, 8);                       \
      l##SUF[r] = l##SUF[r] * al + rs;                                        \
      m##SUF[r] = mn;                                                         \
      _Pragma("unroll")                                                       \
      for (int n = 0; n < 4; ++n) {                                           \
        o##SUF[n][r] *= al;                                                   \
        Pt[qrl][n * 16 + l15] = f2bf(s_[n][r]);                               \
      }                                                                       \
    }                                                                         \
    {                                                                         \
      const short8 p0_ = *(const short8*)&Pt[wid * 16 + l15][lhi * 8];        \
      const short8 p1_ = *(const short8*)&Pt[wid * 16 + l15][32 + lhi * 8];   \
      _Pragma("unroll")                                                       \
      for (int n = 0; n < 4; ++n) {                                           \
        const int dv = n * 16 + l15;                                          \
        const int sw = (dv & 7) << 4;                                         \
        const short8 v0_ = *(const short8*)((const char*)Vt + dv * 128 + ((lhi * 16) ^ sw));      \
        const short8 v1_ = *(const short8*)((const char*)Vt + dv * 128 + ((64 + lhi * 16) ^ sw)); \
        o##SUF[n] = MFMA16(p0_, v0_, o##SUF[n]);                              \
        o##SUF[n] = MFMA16(p1_, v1_, o##SUF[n]);                              \
      }                                                                       \
    }                                                                         \
  } while (0)

// 1D grid of 1024 blocks. XCD-aware mapping: each XCD owns 8 consecutive bh
// (= 2 (b,hkv) K/V slices = 1 MB) so K/V re-reads stay L2-resident.
// Block handles q-tiles qA=bx and qB=31-bx (33 balanced tile-steps each).
__global__ __launch_bounds__(256) void attn_kernel(const ushort* __restrict__ qkv,
                                                   const ushort* __restrict__ vT,
                                                   ushort* __restrict__ out) {
  __shared__ __align__(16) ushort Kt[4096];   // [kv][d] 64x64, XOR-swizzled
  __shared__ __align__(16) ushort Vt[4096];   // [d][kv] 64x64, XOR-swizzled
  __shared__ __align__(16) ushort Pt[64][72];
  const int bid = blockIdx.x;
  const int j = bid >> 3;
  const int bh = (bid & 7) * 8 + (j & 7);     // bijective over 0..63
  const int bx = j >> 3;                      // 0..15
  const int b = bh >> 5, h = bh & 31, hkv = h >> 2;
  const int tid = threadIdx.x;
  const int wid = tid >> 6, lane = tid & 63, l15 = lane & 15, lhi = lane >> 4;
  const int qA = bx, qB = 31 - bx;

  f32x4 oA[4] = {}, oB[4] = {};
  float mA[4], lA[4], mB[4], lB[4];
#pragma unroll
  for (int r = 0; r < 4; ++r) { mA[r] = mB[r] = -1e30f; lA[r] = lB[r] = 0.f; }

  const int srow = tid >> 3, sgrp = tid & 7;
  const int d0s = ((sgrp ^ (srow & 7)) * 8);  // swizzled source column (elems)
  const ushort* kb_g = qkv + (size_t)b * T_SEQ * 2560 + 2048 + hkv * 64;
  const ushort* vb_g = vT + (size_t)(b * 8 + hkv) * 64 * 2048;
  ushort* ldsK = Kt + tid * 8;
  ushort* ldsV = Vt + tid * 8;

  for (int kt = 0; kt <= qB; ++kt) {
    const int ktb = kt * 64;
    gload_lds16(kb_g + (size_t)(ktb + srow) * 2560 + d0s, ldsK);
    gload_lds16(kb_g + (size_t)(ktb + 32 + srow) * 2560 + d0s, ldsK + 2048);
    gload_lds16(vb_g + (size_t)srow * 2048 + ktb + d0s, ldsV);
    gload_lds16(vb_g + (size_t)(32 + srow) * 2048 + ktb + d0s, ldsV + 2048);
    __syncthreads();
    PROCESS(B, kt == qB);
    if (kt <= qA) PROCESS(A, kt == qA);
    __syncthreads();
  }

#pragma unroll
  for (int r = 0; r < 4; ++r) {
    const float invA = 1.f / lA[r];
    const size_t orowA = (size_t)(b * T_SEQ + qA * 64 + wid * 16 + lhi * 4 + r);
#pragma unroll
    for (int n = 0; n < 4; ++n)
      out[orowA * 2048 + h * 64 + n * 16 + l15] = f2bf(oA[n][r] * invA);
  }
#pragma unroll
  for (int r = 0; r < 4; ++r) {
    const float invB = 1.f / lB[r];
    const size_t orowB = (size_t)(b * T_SEQ + qB * 64 + wid * 16 + lhi * 4 + r);
#pragma unroll
    for (int n = 0; n < 4; ++n)
      out[orowB * 2048 + h * 64 + n * 16 + l15] = f2bf(oB[n][r] * invB);
  }
}

// -----------------------------------------------------------------------
extern "C" void kernel_launch(void* const* d_in, const int* in_sizes, int n_in,
                              void* d_out, int out_size, void* d_ws, size_t ws_size,
                              hipStream_t stream) {
  const float* hs   = (const float*)d_in[0];
  const float* cosb = (const float*)d_in[1];
  const float* sinb = (const float*)d_in[2];
  const float* wq   = (const float*)d_in[3];
  const float* wk   = (const float*)d_in[4];
  const float* wv   = (const float*)d_in[5];
  const float* wo   = (const float*)d_in[6];
  float* out = (float*)d_out;

  char* ws = (char*)d_ws;
  ushort* hsb   = (ushort*)(ws);                    // 4096x2048 bf16 (16 MB)
  ushort* wqkvb = (ushort*)(ws + 16777216);         // 3072x2048 bf16 (12.6 MB)
  ushort* wob   = (ushort*)(ws + 29360128);         // 2048x2048 bf16 (8.4 MB)
  ushort* qkvQK = (ushort*)(ws + 37748736);         // 4096x2560 bf16 (21 MB)
  ushort* vTb   = (ushort*)(ws + 58720256);         // 16x64x2048 bf16 (4 MB)
  ushort* attno = hsb;  // alias: hs_bf16 dead after QKV GEMM

  cast_kernel<<<8192, 256, 0, stream>>>(hs, hsb, 2097152);
  cast_kernel<<<4096, 256, 0, stream>>>(wq, wqkvb, 1048576);
  cast_kernel<<<1024, 256, 0, stream>>>(wk, wqkvb + 4194304, 262144);
  cast_kernel<<<1024, 256, 0, stream>>>(wv, wqkvb + 5242880, 262144);
  cast_kernel<<<4096, 256, 0, stream>>>(wo, wob, 1048576);

  // fused QKV projection; V columns routed transposed to vTb
  gemm_bt<2, ushort><<<dim3(24, 32), 256, 0, stream>>>(hsb, wqkvb, qkvQK, vTb,
                                                       4096, 3072, 2048);

  rope_kernel<<<4096, 256, 0, stream>>>(qkvQK, cosb, sinb);

  attn_kernel<<<1024, 256, 0, stream>>>(qkvQK, vTb, attno);

  gemm_bt<0, float><<<dim3(16, 32), 256, 0, stream>>>(attno, wob, out, nullptr,
                                                      4096, 2048, 2048);
}

// Round 10
// 341.797 us; speedup vs baseline: 1.4871x; 1.1255x over previous
//
#include <hip/hip_runtime.h>
#include <hip/hip_bf16.h>

#define T_SEQ 2048
#define HID_DIM 2048

typedef __attribute__((ext_vector_type(8))) short short8;
typedef __attribute__((ext_vector_type(4))) short short4v;
typedef __attribute__((ext_vector_type(4))) float f32x4;

#define MFMA16(a, b, c) __builtin_amdgcn_mfma_f32_16x16x32_bf16((a), (b), (c), 0, 0, 0)

static __device__ __forceinline__ ushort f2bf(float f) {
  union { __hip_bfloat16 h; ushort u; } un;
  un.h = __float2bfloat16(f);
  return un.u;
}
static __device__ __forceinline__ float bf2f(ushort u) {
  union { ushort u; __hip_bfloat16 h; } un;
  un.u = u;
  return __bfloat162float(un.h);
}

static __device__ __forceinline__ void gload_lds16(const void* g, void* l) {
  __builtin_amdgcn_global_load_lds(
      (const __attribute__((address_space(1))) void*)g,
      (__attribute__((address_space(3))) void*)l, 16, 0, 0);
}

// ---------------- fp32 -> bf16 cast (float4 vectorized) ----------------
__global__ __launch_bounds__(256) void cast_kernel(const float* __restrict__ in,
                                                   ushort* __restrict__ out, int n4) {
  int i = blockIdx.x * 256 + threadIdx.x;
  if (i >= n4) return;
  const float4 v = reinterpret_cast<const float4*>(in)[i];
  ushort4 o;
  o.x = f2bf(v.x); o.y = f2bf(v.y); o.z = f2bf(v.z); o.w = f2bf(v.w);
  reinterpret_cast<ushort4*>(out)[i] = o;
}

// ---------------- GEMM: C[M,N] = A[M,K] * W[N,K]^T ----------------------
__device__ __forceinline__ void store_c(float* p, float v) { *p = v; }
__device__ __forceinline__ void store_c(ushort* p, float v) { *p = f2bf(v); }

template <int MODE, typename OutT>
__global__ __launch_bounds__(256) void gemm_bt(const ushort* __restrict__ A,
                                               const ushort* __restrict__ W,
                                               OutT* __restrict__ C,
                                               ushort* __restrict__ vTout,
                                               int M, int N, int K) {
  __shared__ __align__(16) ushort As[128][32];
  __shared__ __align__(16) ushort Bs[128][32];
  const int brow = blockIdx.y * 128, bcol = blockIdx.x * 128;
  const int tid = threadIdx.x;
  const int wid = tid >> 6, lane = tid & 63, l15 = lane & 15, lhi = lane >> 4;
  const int wr = wid >> 1, wc = wid & 1;
  const int srow = tid >> 2, scol = (tid & 3) * 8;

  f32x4 acc[4][4] = {};

  const ushort* a0 = A + (size_t)(brow + srow) * K + scol;
  const ushort* a1 = A + (size_t)(brow + 64 + srow) * K + scol;
  const ushort* w0 = W + (size_t)(bcol + srow) * K + scol;
  const ushort* w1 = W + (size_t)(bcol + 64 + srow) * K + scol;
  ushort* lA0 = &As[0][0] + tid * 8;
  ushort* lA1 = &As[0][0] + 2048 + tid * 8;
  ushort* lB0 = &Bs[0][0] + tid * 8;
  ushort* lB1 = &Bs[0][0] + 2048 + tid * 8;

  for (int k0 = 0; k0 < K; k0 += 32) {
    gload_lds16(a0 + k0, lA0);
    gload_lds16(a1 + k0, lA1);
    gload_lds16(w0 + k0, lB0);
    gload_lds16(w1 + k0, lB1);
    __syncthreads();
    short8 af[4], bfr[4];
#pragma unroll
    for (int m = 0; m < 4; ++m)
      af[m] = *(const short8*)&As[wr * 64 + m * 16 + l15][lhi * 8];
#pragma unroll
    for (int n = 0; n < 4; ++n)
      bfr[n] = *(const short8*)&Bs[wc * 64 + n * 16 + l15][lhi * 8];
#pragma unroll
    for (int m = 0; m < 4; ++m)
#pragma unroll
      for (int n = 0; n < 4; ++n)
        acc[m][n] = MFMA16(af[m], bfr[n], acc[m][n]);
    __syncthreads();
  }

  if (MODE == 2 && bcol >= 2560) {
    // V projection -> vT[(b*8+hkv)*64 + d][t]
#pragma unroll
    for (int m = 0; m < 4; ++m) {
      const int row = brow + wr * 64 + m * 16 + lhi * 4;
      const int bb = row >> 11, t = row & 2047;
#pragma unroll
      for (int n = 0; n < 4; ++n) {
        const int cv = bcol + wc * 64 + n * 16 + l15 - 2560;
        const int hk = cv >> 6, dd = cv & 63;
        ushort4 o;
        o.x = f2bf(acc[m][n][0]); o.y = f2bf(acc[m][n][1]);
        o.z = f2bf(acc[m][n][2]); o.w = f2bf(acc[m][n][3]);
        *(ushort4*)&vTout[(size_t)((bb * 8 + hk) * 64 + dd) * 2048 + t] = o;
      }
    }
  } else {
    const int cstride = (MODE == 2) ? 2560 : N;
#pragma unroll
    for (int m = 0; m < 4; ++m) {
      const int row = brow + wr * 64 + m * 16 + lhi * 4;
#pragma unroll
      for (int n = 0; n < 4; ++n) {
        const int col = bcol + wc * 64 + n * 16 + l15;
#pragma unroll
        for (int r = 0; r < 4; ++r)
          store_c(&C[(size_t)(row + r) * cstride + col], acc[m][n][r]);
      }
    }
  }
}

// ---------------- RoPE in-place on QK buffer (stride 2560); Q pre-scaled -
__global__ __launch_bounds__(256) void rope_kernel(ushort* __restrict__ qkv,
                                                   const float* __restrict__ ct,
                                                   const float* __restrict__ st) {
  const int bt = blockIdx.x;
  ushort* row = qkv + (size_t)bt * 2560;
  const float* c = ct + (size_t)bt * 64;
  const float* s = st + (size_t)bt * 64;
  const int tid = threadIdx.x;
#pragma unroll
  for (int it = 0; it < 5; ++it) {
    const int idx = it * 256 + tid;
    const bool isQ = idx < 1024;
    const int sub = isQ ? idx : idx - 1024;
    const int hh = sub >> 5;
    const int p = sub & 31;
    const int col = (isQ ? 0 : 2048) + hh * 64 + p;
    const float x1 = bf2f(row[col]);
    const float x2 = bf2f(row[col + 32]);
    const float cc = c[p], ss = s[p];
    float y1 = x1 * cc - x2 * ss;
    float y2 = x2 * cc + x1 * ss;
    if (isQ) { y1 *= 0.125f; y2 *= 0.125f; }
    row[col] = f2bf(y1);
    row[col + 32] = f2bf(y2);
  }
}

// ---------------- causal GQA flash attention ---------------------------
// Swapped-operand QK^T: S^T = mfma(K_frag, Q_frag) -> C[kv][q]. Lane layout:
//   A = K   : row kv = l15 (block n*16), d = 8*lhi..+8
//   B = Q^T : d, q-col = l15  (wave's q-row = wid*16 + l15)
//   D = S^T : kv = n*16 + 4*lhi + r, q = l15
// Each lane owns ALL 64 kv of ONE q-row -> in-lane max/sum tree + 2
// shuffles (xor16/32); softmax state 1 scalar/lane; P k-contiguous
// (4x ds_write_b64). Rescale factors broadcast with 4 shuffles to the
// o-row layout (q = 4*lhi+r).
// ROUND-7 BUGS FIXED: (1) causal mask must compare kv against the FULL
// local q index wid*16 + l15 (was l15 -> over-masked waves 1-3);
// (2) Pt row stride must be 16B-aligned for the short8 PV reads ->
// 72 elems (144 B), not 68 (136 B).
#define PROCESS(SUF, diag_) do {                                              \
    f32x4 s_[4] = {};                                                         \
    __builtin_amdgcn_s_setprio(1);                                            \
    _Pragma("unroll")                                                         \
    for (int n = 0; n < 4; ++n) {                                             \
      const short8 k0_ = *(const short8*)(KtB + n * 2048 + base0);            \
      const short8 k1_ = *(const short8*)(KtB + n * 2048 + base1);            \
      s_[n] = MFMA16(k0_, q##SUF##0, s_[n]);                                  \
      s_[n] = MFMA16(k1_, q##SUF##1, s_[n]);                                  \
    }                                                                         \
    __builtin_amdgcn_s_setprio(0);                                            \
    if (diag_) {                                                              \
      _Pragma("unroll")                                                       \
      for (int n = 0; n < 4; ++n) {                                           \
        const int kb_ = 16 * n + 4 * lhi;                                     \
        _Pragma("unroll")                                                     \
        for (int r = 0; r < 4; ++r)                                           \
          if (kb_ + r > qloc) s_[n][r] = -1e30f;                              \
      }                                                                       \
    }                                                                         \
    float mx_;                                                                \
    {                                                                         \
      const float m0_ = fmaxf(fmaxf(s_[0][0], s_[0][1]), fmaxf(s_[0][2], s_[0][3])); \
      const float m1_ = fmaxf(fmaxf(s_[1][0], s_[1][1]), fmaxf(s_[1][2], s_[1][3])); \
      const float m2_ = fmaxf(fmaxf(s_[2][0], s_[2][1]), fmaxf(s_[2][2], s_[2][3])); \
      const float m3_ = fmaxf(fmaxf(s_[3][0], s_[3][1]), fmaxf(s_[3][2], s_[3][3])); \
      mx_ = fmaxf(fmaxf(m0_, m1_), fmaxf(m2_, m3_));                          \
    }                                                                         \
    mx_ = fmaxf(mx_, __shfl_xor(mx_, 16));                                    \
    mx_ = fmaxf(mx_, __shfl_xor(mx_, 32));                                    \
    const float mn_ = fmaxf(mS##SUF, mx_);                                    \
    const float al_ = __expf(mS##SUF - mn_);                                  \
    _Pragma("unroll")                                                         \
    for (int n = 0; n < 4; ++n) {                                             \
      s_[n][0] = __expf(s_[n][0] - mn_);                                      \
      s_[n][1] = __expf(s_[n][1] - mn_);                                      \
      s_[n][2] = __expf(s_[n][2] - mn_);                                      \
      s_[n][3] = __expf(s_[n][3] - mn_);                                      \
    }                                                                         \
    float rs_;                                                                \
    {                                                                         \
      const float t0_ = (s_[0][0] + s_[0][1]) + (s_[0][2] + s_[0][3]);        \
      const float t1_ = (s_[1][0] + s_[1][1]) + (s_[1][2] + s_[1][3]);        \
      const float t2_ = (s_[2][0] + s_[2][1]) + (s_[2][2] + s_[2][3]);        \
      const float t3_ = (s_[3][0] + s_[3][1]) + (s_[3][2] + s_[3][3]);        \
      rs_ = (t0_ + t1_) + (t2_ + t3_);                                        \
    }                                                                         \
    rs_ += __shfl_xor(rs_, 16);                                               \
    rs_ += __shfl_xor(rs_, 32);                                               \
    lS##SUF = lS##SUF * al_ + rs_;                                            \
    mS##SUF = mn_;                                                            \
    _Pragma("unroll")                                                         \
    for (int n = 0; n < 4; ++n) {                                             \
      short4v pk_;                                                            \
      pk_[0] = (short)f2bf(s_[n][0]);                                         \
      pk_[1] = (short)f2bf(s_[n][1]);                                         \
      pk_[2] = (short)f2bf(s_[n][2]);                                         \
      pk_[3] = (short)f2bf(s_[n][3]);                                         \
      *(short4v*)(PtB + prow + 32 * n + 8 * lhi) = pk_;                       \
    }                                                                         \
    const float al0_ = __shfl(al_, 4 * lhi + 0);                              \
    const float al1_ = __shfl(al_, 4 * lhi + 1);                              \
    const float al2_ = __shfl(al_, 4 * lhi + 2);                              \
    const float al3_ = __shfl(al_, 4 * lhi + 3);                              \
    _Pragma("unroll")                                                         \
    for (int n = 0; n < 4; ++n) {                                             \
      o##SUF[n][0] *= al0_;                                                   \
      o##SUF[n][1] *= al1_;                                                   \
      o##SUF[n][2] *= al2_;                                                   \
      o##SUF[n][3] *= al3_;                                                   \
    }                                                                         \
    {                                                                         \
      const short8 p0_ = *(const short8*)(PtB + prow + 16 * lhi);             \
      const short8 p1_ = *(const short8*)(PtB + prow + 64 + 16 * lhi);        \
      __builtin_amdgcn_s_setprio(1);                                          \
      _Pragma("unroll")                                                       \
      for (int n = 0; n < 4; ++n) {                                           \
        const short8 v0_ = *(const short8*)(VtB + n * 2048 + base0);          \
        const short8 v1_ = *(const short8*)(VtB + n * 2048 + base1);          \
        o##SUF[n] = MFMA16(p0_, v0_, o##SUF[n]);                              \
        o##SUF[n] = MFMA16(p1_, v1_, o##SUF[n]);                              \
      }                                                                       \
      __builtin_amdgcn_s_setprio(0);                                          \
    }                                                                         \
  } while (0)

// 1D grid of 1024 blocks. XCD-aware mapping: each XCD owns 8 consecutive bh
// (= 2 (b,hkv) K/V slices = 1 MB, L2-resident). Block handles q-tiles
// qA=bx and qB=31-bx (33 balanced PROCESS calls each).
__global__ __launch_bounds__(256) void attn_kernel(const ushort* __restrict__ qkv,
                                                   const ushort* __restrict__ vT,
                                                   ushort* __restrict__ out) {
  __shared__ __align__(16) ushort Kt[4096];     // [kv][d] 64x64, XOR-swizzled
  __shared__ __align__(16) ushort Vt[4096];     // [d][kv] 64x64, XOR-swizzled
  __shared__ __align__(16) ushort Pt[64 * 72];  // [q][k] stride 72 (144 B, 16B-aligned)
  const int bid = blockIdx.x;
  const int j = bid >> 3;
  const int bh = (bid & 7) * 8 + (j & 7);     // bijective over 0..63
  const int bx = j >> 3;                      // 0..15
  const int b = bh >> 5, h = bh & 31, hkv = h >> 2;
  const int tid = threadIdx.x;
  const int wid = tid >> 6, lane = tid & 63, l15 = lane & 15, lhi = lane >> 4;
  const int qA = bx, qB = 31 - bx;
  const int qloc = wid * 16 + l15;            // this lane's local q index (mask!)

  // Q fragments in registers for the whole kernel
  short8 qA0, qA1, qB0, qB1;
  {
    const size_t offA = (size_t)(b * T_SEQ + qA * 64 + qloc) * 2560 + h * 64;
    qA0 = *(const short8*)(qkv + offA + lhi * 8);
    qA1 = *(const short8*)(qkv + offA + 32 + lhi * 8);
    const size_t offB = (size_t)(b * T_SEQ + qB * 64 + qloc) * 2560 + h * 64;
    qB0 = *(const short8*)(qkv + offB + lhi * 8);
    qB1 = *(const short8*)(qkv + offB + 32 + lhi * 8);
  }

  f32x4 oA[4] = {}, oB[4] = {};
  float mSA = -1e30f, lSA = 0.f, mSB = -1e30f, lSB = 0.f;

  // loop-invariant LDS addresses
  const int swb = (l15 & 7) << 4;
  const int base0 = l15 * 128 + ((lhi * 16) ^ swb);
  const int base1 = l15 * 128 + ((64 + lhi * 16) ^ swb);
  const char* KtB = (const char*)Kt;
  const char* VtB = (const char*)Vt;
  char* PtB = (char*)Pt;
  const int prow = qloc * 144;

  const int srow = tid >> 3, sgrp = tid & 7;
  const int d0s = ((sgrp ^ (srow & 7)) * 8);  // swizzled source column (elems)
  const ushort* kb_g = qkv + (size_t)b * T_SEQ * 2560 + 2048 + hkv * 64;
  const ushort* vb_g = vT + (size_t)(b * 8 + hkv) * 64 * 2048;
  ushort* ldsK = Kt + tid * 8;
  ushort* ldsV = Vt + tid * 8;

  for (int kt = 0; kt <= qB; ++kt) {
    const int ktb = kt * 64;
    gload_lds16(kb_g + (size_t)(ktb + srow) * 2560 + d0s, ldsK);
    gload_lds16(kb_g + (size_t)(ktb + 32 + srow) * 2560 + d0s, ldsK + 2048);
    gload_lds16(vb_g + (size_t)srow * 2048 + ktb + d0s, ldsV);
    gload_lds16(vb_g + (size_t)(32 + srow) * 2048 + ktb + d0s, ldsV + 2048);
    __syncthreads();
    PROCESS(B, kt == qB);
    if (kt <= qA) PROCESS(A, kt == qA);
    __syncthreads();
  }

  {
    const float invA = 1.f / lSA;
    const float i0 = __shfl(invA, 4 * lhi + 0), i1 = __shfl(invA, 4 * lhi + 1);
    const float i2 = __shfl(invA, 4 * lhi + 2), i3 = __shfl(invA, 4 * lhi + 3);
    const size_t orow = (size_t)(b * T_SEQ + qA * 64 + wid * 16 + lhi * 4);
#pragma unroll
    for (int n = 0; n < 4; ++n) {
      out[(orow + 0) * 2048 + h * 64 + n * 16 + l15] = f2bf(oA[n][0] * i0);
      out[(orow + 1) * 2048 + h * 64 + n * 16 + l15] = f2bf(oA[n][1] * i1);
      out[(orow + 2) * 2048 + h * 64 + n * 16 + l15] = f2bf(oA[n][2] * i2);
      out[(orow + 3) * 2048 + h * 64 + n * 16 + l15] = f2bf(oA[n][3] * i3);
    }
  }
  {
    const float invB = 1.f / lSB;
    const float i0 = __shfl(invB, 4 * lhi + 0), i1 = __shfl(invB, 4 * lhi + 1);
    const float i2 = __shfl(invB, 4 * lhi + 2), i3 = __shfl(invB, 4 * lhi + 3);
    const size_t orow = (size_t)(b * T_SEQ + qB * 64 + wid * 16 + lhi * 4);
#pragma unroll
    for (int n = 0; n < 4; ++n) {
      out[(orow + 0) * 2048 + h * 64 + n * 16 + l15] = f2bf(oB[n][0] * i0);
      out[(orow + 1) * 2048 + h * 64 + n * 16 + l15] = f2bf(oB[n][1] * i1);
      out[(orow + 2) * 2048 + h * 64 + n * 16 + l15] = f2bf(oB[n][2] * i2);
      out[(orow + 3) * 2048 + h * 64 + n * 16 + l15] = f2bf(oB[n][3] * i3);
    }
  }
}

// -----------------------------------------------------------------------
extern "C" void kernel_launch(void* const* d_in, const int* in_sizes, int n_in,
                              void* d_out, int out_size, void* d_ws, size_t ws_size,
                              hipStream_t stream) {
  const float* hs   = (const float*)d_in[0];
  const float* cosb = (const float*)d_in[1];
  const float* sinb = (const float*)d_in[2];
  const float* wq   = (const float*)d_in[3];
  const float* wk   = (const float*)d_in[4];
  const float* wv   = (const float*)d_in[5];
  const float* wo   = (const float*)d_in[6];
  float* out = (float*)d_out;

  char* ws = (char*)d_ws;
  ushort* hsb   = (ushort*)(ws);                    // 4096x2048 bf16 (16 MB)
  ushort* wqkvb = (ushort*)(ws + 16777216);         // 3072x2048 bf16 (12.6 MB)
  ushort* wob   = (ushort*)(ws + 29360128);         // 2048x2048 bf16 (8.4 MB)
  ushort* qkvQK = (ushort*)(ws + 37748736);         // 4096x2560 bf16 (21 MB)
  ushort* vTb   = (ushort*)(ws + 58720256);         // 16x64x2048 bf16 (4 MB)
  ushort* attno = hsb;  // alias: hs_bf16 dead after QKV GEMM

  cast_kernel<<<8192, 256, 0, stream>>>(hs, hsb, 2097152);
  cast_kernel<<<4096, 256, 0, stream>>>(wq, wqkvb, 1048576);
  cast_kernel<<<1024, 256, 0, stream>>>(wk, wqkvb + 4194304, 262144);
  cast_kernel<<<1024, 256, 0, stream>>>(wv, wqkvb + 5242880, 262144);
  cast_kernel<<<4096, 256, 0, stream>>>(wo, wob, 1048576);

  // fused QKV projection; V columns routed transposed to vTb
  gemm_bt<2, ushort><<<dim3(24, 32), 256, 0, stream>>>(hsb, wqkvb, qkvQK, vTb,
                                                       4096, 3072, 2048);

  rope_kernel<<<4096, 256, 0, stream>>>(qkvQK, cosb, sinb);

  attn_kernel<<<1024, 256, 0, stream>>>(qkvQK, vTb, attno);

  gemm_bt<0, float><<<dim3(16, 32), 256, 0, stream>>>(attno, wob, out, nullptr,
                                                      4096, 2048, 2048);
}

// Round 11
// 341.252 us; speedup vs baseline: 1.4895x; 1.0016x over previous
//
#include <hip/hip_runtime.h>
#include <hip/hip_bf16.h>

#define T_SEQ 2048
#define HID_DIM 2048

typedef __attribute__((ext_vector_type(8))) short short8;
typedef __attribute__((ext_vector_type(4))) short short4v;
typedef __attribute__((ext_vector_type(4))) float f32x4;

#define MFMA16(a, b, c) __builtin_amdgcn_mfma_f32_16x16x32_bf16((a), (b), (c), 0, 0, 0)

static __device__ __forceinline__ ushort f2bf(float f) {
  union { __hip_bfloat16 h; ushort u; } un;
  un.h = __float2bfloat16(f);
  return un.u;
}
static __device__ __forceinline__ float bf2f(ushort u) {
  union { ushort u; __hip_bfloat16 h; } un;
  un.u = u;
  return __bfloat162float(un.h);
}

static __device__ __forceinline__ void gload_lds16(const void* g, void* l) {
  __builtin_amdgcn_global_load_lds(
      (const __attribute__((address_space(1))) void*)g,
      (__attribute__((address_space(3))) void*)l, 16, 0, 0);
}

// ---------------- fp32 -> bf16 cast (float4 vectorized) ----------------
__global__ __launch_bounds__(256) void cast_kernel(const float* __restrict__ in,
                                                   ushort* __restrict__ out, int n4) {
  int i = blockIdx.x * 256 + threadIdx.x;
  if (i >= n4) return;
  const float4 v = reinterpret_cast<const float4*>(in)[i];
  ushort4 o;
  o.x = f2bf(v.x); o.y = f2bf(v.y); o.z = f2bf(v.z); o.w = f2bf(v.w);
  reinterpret_cast<ushort4*>(out)[i] = o;
}

// ---------------- 256-tile GEMM, counted-vmcnt schedule ------------------
// C[M,N] = A[M,K] * W[N,K]^T. 512 threads = 8 waves (2M x 4N); per-wave
// output 128 x BN/4. Two full K-tile LDS buffers (A+B); per iteration:
//   issue next tile's staging (global_load_lds) -> s_waitcnt vmcnt(COUNTED)
//   -> raw s_barrier (NOT __syncthreads: that drains vmcnt(0) = m97 stall)
//   -> 4 quadrant phases {ds_read frags, setprio1, 16 MFMA, setprio0}
//      (no intra-tile barriers: compute buffer is read-only, staging goes
//       to the other buffer) -> end barrier.
// T2 swizzle col ^= (row&7)<<4 via pre-swizzled global source (linear LDS
// dest, required by global_load_lds) + same XOR on ds_read.
// MODE 0: float C, stride N. MODE 2: QKV split - cols<2560 ushort stride
// 2560; cols>=2560 (V) transposed to vT[b][hkv][d][t].
__device__ __forceinline__ void store_c(float* p, float v) { *p = v; }
__device__ __forceinline__ void store_c(ushort* p, float v) { *p = f2bf(v); }

template <int MODE, int BN, typename OutT>
__global__ __launch_bounds__(512) void gemm8p(const ushort* __restrict__ A,
                                              const ushort* __restrict__ W,
                                              OutT* __restrict__ C,
                                              ushort* __restrict__ vTout,
                                              int M, int N, int K) {
  constexpr int LA = 4;        // A staging chunks (16B) per thread per K-tile
  constexpr int LB = BN / 64;  // B staging chunks per thread per K-tile
  constexpr int NR = BN / 64;  // 16-col fragments per wave
  __shared__ __align__(16) ushort As[2][256 * 64];
  __shared__ __align__(16) ushort Bs[2][BN * 64];
  const int tid = threadIdx.x;
  const int lane = tid & 63, l15 = lane & 15, lhi = lane >> 4;
  const int wid = tid >> 6, wm = wid >> 2, wn = wid & 3;
  const int brow = blockIdx.y * 256, bcol = blockIdx.x * BN;
  const int nkt = K >> 6;

  // staging addresses: chunk c = tid + 512*j; row = c>>3, k16 = c&7;
  // source column pre-swizzled so linear LDS write + XOR read match.
  const ushort* asrc[LA]; ushort* adst[LA];
#pragma unroll
  for (int j = 0; j < LA; ++j) {
    const int c = tid + 512 * j, row = c >> 3, k16 = c & 7;
    asrc[j] = A + (size_t)(brow + row) * K + ((k16 ^ (row & 7)) << 3);
    adst[j] = &As[0][0] + c * 8;
  }
  const ushort* bsrc[LB]; ushort* bdst[LB];
#pragma unroll
  for (int j = 0; j < LB; ++j) {
    const int c = tid + 512 * j, row = c >> 3, k16 = c & 7;
    bsrc[j] = W + (size_t)(bcol + row) * K + ((k16 ^ (row & 7)) << 3);
    bdst[j] = &Bs[0][0] + c * 8;
  }

#define STAGE8(kt_, bf_) do {                                              \
    _Pragma("unroll")                                                      \
    for (int j = 0; j < LA; ++j)                                           \
      gload_lds16(asrc[j] + (kt_) * 64, adst[j] + (bf_) * (256 * 64));     \
    _Pragma("unroll")                                                      \
    for (int j = 0; j < LB; ++j)                                           \
      gload_lds16(bsrc[j] + (kt_) * 64, bdst[j] + (bf_) * (BN * 64));      \
  } while (0)

  f32x4 acc[8][NR] = {};

  STAGE8(0, 0);
  for (int kt = 0; kt < nkt; ++kt) {
    const int bf = kt & 1;
    if (kt + 1 < nkt) {
      STAGE8(kt + 1, bf ^ 1);
      // counted wait: drains tile kt's loads, keeps tile kt+1's in flight
      if constexpr (LA + LB == 8) asm volatile("s_waitcnt vmcnt(8)" ::: "memory");
      else                        asm volatile("s_waitcnt vmcnt(6)" ::: "memory");
    } else {
      asm volatile("s_waitcnt vmcnt(0)" ::: "memory");
    }
    __builtin_amdgcn_s_barrier();
    const char* abuf = (const char*)&As[bf][0];
    const char* bbuf = (const char*)&Bs[bf][0];
#pragma unroll
    for (int mh = 0; mh < 2; ++mh) {
      short8 af[4][2];
#pragma unroll
      for (int mi = 0; mi < 4; ++mi) {
        const int row = wm * 128 + (mh * 4 + mi) * 16 + l15;
        const int sw = (row & 7) << 4;
#pragma unroll
        for (int ks = 0; ks < 2; ++ks)
          af[mi][ks] = *(const short8*)(abuf + row * 128 + ((ks * 64 + lhi * 16) ^ sw));
      }
#pragma unroll
      for (int nh = 0; nh < NR / 2; ++nh) {
        short8 bfrag[2][2];
#pragma unroll
        for (int ni = 0; ni < 2; ++ni) {
          const int rowb = wn * (BN / 4) + (nh * 2 + ni) * 16 + l15;
          const int sw = (rowb & 7) << 4;
#pragma unroll
          for (int ks = 0; ks < 2; ++ks)
            bfrag[ni][ks] = *(const short8*)(bbuf + rowb * 128 + ((ks * 64 + lhi * 16) ^ sw));
        }
        __builtin_amdgcn_s_setprio(1);
#pragma unroll
        for (int ks = 0; ks < 2; ++ks)
#pragma unroll
          for (int mi = 0; mi < 4; ++mi)
#pragma unroll
            for (int ni = 0; ni < 2; ++ni)
              acc[mh * 4 + mi][nh * 2 + ni] =
                  MFMA16(af[mi][ks], bfrag[ni][ks], acc[mh * 4 + mi][nh * 2 + ni]);
        __builtin_amdgcn_s_setprio(0);
      }
    }
    __builtin_amdgcn_s_barrier();
  }
#undef STAGE8

  if (MODE == 2 && bcol >= 2560) {
    // V projection -> vT[(b*8+hkv)*64 + d][t]
#pragma unroll
    for (int mi8 = 0; mi8 < 8; ++mi8) {
      const int row = brow + wm * 128 + mi8 * 16 + lhi * 4;
      const int bb = row >> 11, t = row & 2047;
#pragma unroll
      for (int ni = 0; ni < NR; ++ni) {
        const int cv = bcol + wn * (BN / 4) + ni * 16 + l15 - 2560;
        const int hk = cv >> 6, dd = cv & 63;
        ushort4 o;
        o.x = f2bf(acc[mi8][ni][0]); o.y = f2bf(acc[mi8][ni][1]);
        o.z = f2bf(acc[mi8][ni][2]); o.w = f2bf(acc[mi8][ni][3]);
        *(ushort4*)&vTout[(size_t)((bb * 8 + hk) * 64 + dd) * 2048 + t] = o;
      }
    }
  } else {
    const int cstride = (MODE == 2) ? 2560 : N;
#pragma unroll
    for (int mi8 = 0; mi8 < 8; ++mi8) {
      const int row = brow + wm * 128 + mi8 * 16 + lhi * 4;
#pragma unroll
      for (int ni = 0; ni < NR; ++ni) {
        const int col = bcol + wn * (BN / 4) + ni * 16 + l15;
#pragma unroll
        for (int r = 0; r < 4; ++r)
          store_c(&C[(size_t)(row + r) * cstride + col], acc[mi8][ni][r]);
      }
    }
  }
}

// ---------------- RoPE in-place on QK buffer (stride 2560); Q pre-scaled -
__global__ __launch_bounds__(256) void rope_kernel(ushort* __restrict__ qkv,
                                                   const float* __restrict__ ct,
                                                   const float* __restrict__ st) {
  const int bt = blockIdx.x;
  ushort* row = qkv + (size_t)bt * 2560;
  const float* c = ct + (size_t)bt * 64;
  const float* s = st + (size_t)bt * 64;
  const int tid = threadIdx.x;
#pragma unroll
  for (int it = 0; it < 5; ++it) {
    const int idx = it * 256 + tid;
    const bool isQ = idx < 1024;
    const int sub = isQ ? idx : idx - 1024;
    const int hh = sub >> 5;
    const int p = sub & 31;
    const int col = (isQ ? 0 : 2048) + hh * 64 + p;
    const float x1 = bf2f(row[col]);
    const float x2 = bf2f(row[col + 32]);
    const float cc = c[p], ss = s[p];
    float y1 = x1 * cc - x2 * ss;
    float y2 = x2 * cc + x1 * ss;
    if (isQ) { y1 *= 0.125f; y2 *= 0.125f; }
    row[col] = f2bf(y1);
    row[col + 32] = f2bf(y2);
  }
}

// ---------------- causal GQA flash attention (unchanged from round 10) --
#define PROCESS(SUF, diag_) do {                                              \
    f32x4 s_[4] = {};                                                         \
    __builtin_amdgcn_s_setprio(1);                                            \
    _Pragma("unroll")                                                         \
    for (int n = 0; n < 4; ++n) {                                             \
      const short8 k0_ = *(const short8*)(KtB + n * 2048 + base0);            \
      const short8 k1_ = *(const short8*)(KtB + n * 2048 + base1);            \
      s_[n] = MFMA16(k0_, q##SUF##0, s_[n]);                                  \
      s_[n] = MFMA16(k1_, q##SUF##1, s_[n]);                                  \
    }                                                                         \
    __builtin_amdgcn_s_setprio(0);                                            \
    if (diag_) {                                                              \
      _Pragma("unroll")                                                       \
      for (int n = 0; n < 4; ++n) {                                           \
        const int kb_ = 16 * n + 4 * lhi;                                     \
        _Pragma("unroll")                                                     \
        for (int r = 0; r < 4; ++r)                                           \
          if (kb_ + r > qloc) s_[n][r] = -1e30f;                              \
      }                                                                       \
    }                                                                         \
    float mx_;                                                                \
    {                                                                         \
      const float m0_ = fmaxf(fmaxf(s_[0][0], s_[0][1]), fmaxf(s_[0][2], s_[0][3])); \
      const float m1_ = fmaxf(fmaxf(s_[1][0], s_[1][1]), fmaxf(s_[1][2], s_[1][3])); \
      const float m2_ = fmaxf(fmaxf(s_[2][0], s_[2][1]), fmaxf(s_[2][2], s_[2][3])); \
      const float m3_ = fmaxf(fmaxf(s_[3][0], s_[3][1]), fmaxf(s_[3][2], s_[3][3])); \
      mx_ = fmaxf(fmaxf(m0_, m1_), fmaxf(m2_, m3_));                          \
    }                                                                         \
    mx_ = fmaxf(mx_, __shfl_xor(mx_, 16));                                    \
    mx_ = fmaxf(mx_, __shfl_xor(mx_, 32));                                    \
    const float mn_ = fmaxf(mS##SUF, mx_);                                    \
    const float al_ = __expf(mS##SUF - mn_);                                  \
    _Pragma("unroll")                                                         \
    for (int n = 0; n < 4; ++n) {                                             \
      s_[n][0] = __expf(s_[n][0] - mn_);                                      \
      s_[n][1] = __expf(s_[n][1] - mn_);                                      \
      s_[n][2] = __expf(s_[n][2] - mn_);                                      \
      s_[n][3] = __expf(s_[n][3] - mn_);                                      \
    }                                                                         \
    float rs_;                                                                \
    {                                                                         \
      const float t0_ = (s_[0][0] + s_[0][1]) + (s_[0][2] + s_[0][3]);        \
      const float t1_ = (s_[1][0] + s_[1][1]) + (s_[1][2] + s_[1][3]);        \
      const float t2_ = (s_[2][0] + s_[2][1]) + (s_[2][2] + s_[2][3]);        \
      const float t3_ = (s_[3][0] + s_[3][1]) + (s_[3][2] + s_[3][3]);        \
      rs_ = (t0_ + t1_) + (t2_ + t3_);                                        \
    }                                                                         \
    rs_ += __shfl_xor(rs_, 16);                                               \
    rs_ += __shfl_xor(rs_, 32);                                               \
    lS##SUF = lS##SUF * al_ + rs_;                                            \
    mS##SUF = mn_;                                                            \
    _Pragma("unroll")                                                         \
    for (int n = 0; n < 4; ++n) {                                             \
      short4v pk_;                                                            \
      pk_[0] = (short)f2bf(s_[n][0]);                                         \
      pk_[1] = (short)f2bf(s_[n][1]);                                         \
      pk_[2] = (short)f2bf(s_[n][2]);                                         \
      pk_[3] = (short)f2bf(s_[n][3]);                                         \
      *(short4v*)(PtB + prow + 32 * n + 8 * lhi) = pk_;                       \
    }                                                                         \
    const float al0_ = __shfl(al_, 4 * lhi + 0);                              \
    const float al1_ = __shfl(al_, 4 * lhi + 1);                              \
    const float al2_ = __shfl(al_, 4 * lhi + 2);                              \
    const float al3_ = __shfl(al_, 4 * lhi + 3);                              \
    _Pragma("unroll")                                                         \
    for (int n = 0; n < 4; ++n) {                                             \
      o##SUF[n][0] *= al0_;                                                   \
      o##SUF[n][1] *= al1_;                                                   \
      o##SUF[n][2] *= al2_;                                                   \
      o##SUF[n][3] *= al3_;                                                   \
    }                                                                         \
    {                                                                         \
      const short8 p0_ = *(const short8*)(PtB + prow + 16 * lhi);             \
      const short8 p1_ = *(const short8*)(PtB + prow + 64 + 16 * lhi);        \
      __builtin_amdgcn_s_setprio(1);                                          \
      _Pragma("unroll")                                                       \
      for (int n = 0; n < 4; ++n) {                                           \
        const short8 v0_ = *(const short8*)(VtB + n * 2048 + base0);          \
        const short8 v1_ = *(const short8*)(VtB + n * 2048 + base1);          \
        o##SUF[n] = MFMA16(p0_, v0_, o##SUF[n]);                              \
        o##SUF[n] = MFMA16(p1_, v1_, o##SUF[n]);                              \
      }                                                                       \
      __builtin_amdgcn_s_setprio(0);                                          \
    }                                                                         \
  } while (0)

__global__ __launch_bounds__(256) void attn_kernel(const ushort* __restrict__ qkv,
                                                   const ushort* __restrict__ vT,
                                                   ushort* __restrict__ out) {
  __shared__ __align__(16) ushort Kt[4096];     // [kv][d] 64x64, XOR-swizzled
  __shared__ __align__(16) ushort Vt[4096];     // [d][kv] 64x64, XOR-swizzled
  __shared__ __align__(16) ushort Pt[64 * 72];  // [q][k] stride 72 (144 B)
  const int bid = blockIdx.x;
  const int j = bid >> 3;
  const int bh = (bid & 7) * 8 + (j & 7);     // bijective over 0..63
  const int bx = j >> 3;                      // 0..15
  const int b = bh >> 5, h = bh & 31, hkv = h >> 2;
  const int tid = threadIdx.x;
  const int wid = tid >> 6, lane = tid & 63, l15 = lane & 15, lhi = lane >> 4;
  const int qA = bx, qB = 31 - bx;
  const int qloc = wid * 16 + l15;

  short8 qA0, qA1, qB0, qB1;
  {
    const size_t offA = (size_t)(b * T_SEQ + qA * 64 + qloc) * 2560 + h * 64;
    qA0 = *(const short8*)(qkv + offA + lhi * 8);
    qA1 = *(const short8*)(qkv + offA + 32 + lhi * 8);
    const size_t offB = (size_t)(b * T_SEQ + qB * 64 + qloc) * 2560 + h * 64;
    qB0 = *(const short8*)(qkv + offB + lhi * 8);
    qB1 = *(const short8*)(qkv + offB + 32 + lhi * 8);
  }

  f32x4 oA[4] = {}, oB[4] = {};
  float mSA = -1e30f, lSA = 0.f, mSB = -1e30f, lSB = 0.f;

  const int swb = (l15 & 7) << 4;
  const int base0 = l15 * 128 + ((lhi * 16) ^ swb);
  const int base1 = l15 * 128 + ((64 + lhi * 16) ^ swb);
  const char* KtB = (const char*)Kt;
  const char* VtB = (const char*)Vt;
  char* PtB = (char*)Pt;
  const int prow = qloc * 144;

  const int srow = tid >> 3, sgrp = tid & 7;
  const int d0s = ((sgrp ^ (srow & 7)) * 8);
  const ushort* kb_g = qkv + (size_t)b * T_SEQ * 2560 + 2048 + hkv * 64;
  const ushort* vb_g = vT + (size_t)(b * 8 + hkv) * 64 * 2048;
  ushort* ldsK = Kt + tid * 8;
  ushort* ldsV = Vt + tid * 8;

  for (int kt = 0; kt <= qB; ++kt) {
    const int ktb = kt * 64;
    gload_lds16(kb_g + (size_t)(ktb + srow) * 2560 + d0s, ldsK);
    gload_lds16(kb_g + (size_t)(ktb + 32 + srow) * 2560 + d0s, ldsK + 2048);
    gload_lds16(vb_g + (size_t)srow * 2048 + ktb + d0s, ldsV);
    gload_lds16(vb_g + (size_t)(32 + srow) * 2048 + ktb + d0s, ldsV + 2048);
    __syncthreads();
    PROCESS(B, kt == qB);
    if (kt <= qA) PROCESS(A, kt == qA);
    __syncthreads();
  }

  {
    const float invA = 1.f / lSA;
    const float i0 = __shfl(invA, 4 * lhi + 0), i1 = __shfl(invA, 4 * lhi + 1);
    const float i2 = __shfl(invA, 4 * lhi + 2), i3 = __shfl(invA, 4 * lhi + 3);
    const size_t orow = (size_t)(b * T_SEQ + qA * 64 + wid * 16 + lhi * 4);
#pragma unroll
    for (int n = 0; n < 4; ++n) {
      out[(orow + 0) * 2048 + h * 64 + n * 16 + l15] = f2bf(oA[n][0] * i0);
      out[(orow + 1) * 2048 + h * 64 + n * 16 + l15] = f2bf(oA[n][1] * i1);
      out[(orow + 2) * 2048 + h * 64 + n * 16 + l15] = f2bf(oA[n][2] * i2);
      out[(orow + 3) * 2048 + h * 64 + n * 16 + l15] = f2bf(oA[n][3] * i3);
    }
  }
  {
    const float invB = 1.f / lSB;
    const float i0 = __shfl(invB, 4 * lhi + 0), i1 = __shfl(invB, 4 * lhi + 1);
    const float i2 = __shfl(invB, 4 * lhi + 2), i3 = __shfl(invB, 4 * lhi + 3);
    const size_t orow = (size_t)(b * T_SEQ + qB * 64 + wid * 16 + lhi * 4);
#pragma unroll
    for (int n = 0; n < 4; ++n) {
      out[(orow + 0) * 2048 + h * 64 + n * 16 + l15] = f2bf(oB[n][0] * i0);
      out[(orow + 1) * 2048 + h * 64 + n * 16 + l15] = f2bf(oB[n][1] * i1);
      out[(orow + 2) * 2048 + h * 64 + n * 16 + l15] = f2bf(oB[n][2] * i2);
      out[(orow + 3) * 2048 + h * 64 + n * 16 + l15] = f2bf(oB[n][3] * i3);
    }
  }
}

// -----------------------------------------------------------------------
extern "C" void kernel_launch(void* const* d_in, const int* in_sizes, int n_in,
                              void* d_out, int out_size, void* d_ws, size_t ws_size,
                              hipStream_t stream) {
  const float* hs   = (const float*)d_in[0];
  const float* cosb = (const float*)d_in[1];
  const float* sinb = (const float*)d_in[2];
  const float* wq   = (const float*)d_in[3];
  const float* wk   = (const float*)d_in[4];
  const float* wv   = (const float*)d_in[5];
  const float* wo   = (const float*)d_in[6];
  float* out = (float*)d_out;

  char* ws = (char*)d_ws;
  ushort* hsb   = (ushort*)(ws);                    // 4096x2048 bf16 (16 MB)
  ushort* wqkvb = (ushort*)(ws + 16777216);         // 3072x2048 bf16 (12.6 MB)
  ushort* wob   = (ushort*)(ws + 29360128);         // 2048x2048 bf16 (8.4 MB)
  ushort* qkvQK = (ushort*)(ws + 37748736);         // 4096x2560 bf16 (21 MB)
  ushort* vTb   = (ushort*)(ws + 58720256);         // 16x64x2048 bf16 (4 MB)
  ushort* attno = hsb;  // alias: hs_bf16 dead after QKV GEMM

  cast_kernel<<<8192, 256, 0, stream>>>(hs, hsb, 2097152);
  cast_kernel<<<4096, 256, 0, stream>>>(wq, wqkvb, 1048576);
  cast_kernel<<<1024, 256, 0, stream>>>(wk, wqkvb + 4194304, 262144);
  cast_kernel<<<1024, 256, 0, stream>>>(wv, wqkvb + 5242880, 262144);
  cast_kernel<<<4096, 256, 0, stream>>>(wo, wob, 1048576);

  // fused QKV projection (256x256 tiles); V columns routed transposed to vTb
  gemm8p<2, 256, ushort><<<dim3(12, 16), 512, 0, stream>>>(hsb, wqkvb, qkvQK,
                                                           vTb, 4096, 3072, 2048);

  rope_kernel<<<4096, 256, 0, stream>>>(qkvQK, cosb, sinb);

  attn_kernel<<<1024, 256, 0, stream>>>(qkvQK, vTb, attno);

  // output projection (256x128 tiles, exactly 1 block/CU) -> fp32 out
  gemm8p<0, 128, float><<<dim3(16, 16), 512, 0, stream>>>(attno, wob, out,
                                                          nullptr, 4096, 2048, 2048);
}